// Round 2
// baseline (1813.806 us; speedup 1.0000x reference)
//
#include <hip/hip_runtime.h>

constexpr int CC = 512;   // channels
constexpr int KK = 64;    // bases
constexpr int NN = 4096;  // h*w
constexpr int BB = 16;    // batch

// workspace layout (floats)
constexpr size_t XF_OFF    = 0;                              // 16*512*4096 (also reused as XR)
constexpr size_t Z_OFF     = (size_t)BB * CC * NN;           // 16*4096*64
constexpr size_t MU_OFF    = Z_OFF + (size_t)BB * NN * KK;   // 16*512*64
constexpr size_t MUACC_OFF = MU_OFF + (size_t)BB * CC * KK;  // 16*512*64
constexpr size_t ZSUM_OFF  = MUACC_OFF + (size_t)BB * CC * KK; // 16*64

__global__ void k_mu_bcast(const float* __restrict__ mu_in, float* __restrict__ mu) {
    int idx = blockIdx.x * 256 + threadIdx.x;
    if (idx < CC * KK) {
        float v = mu_in[idx];
        for (int b = 0; b < BB; ++b) mu[(size_t)b * CC * KK + idx] = v;
    }
}

// conv1: XF[b,o,n] = sum_c W[o,c] * X[b,c,n] + bias[o]
__global__ __launch_bounds__(256) void k_conv1(
    const float* __restrict__ W, const float* __restrict__ bias,
    const float* __restrict__ X, float* __restrict__ XF) {
    int bn = blockIdx.x * 64;
    int bm = blockIdx.y * 64;
    int b  = blockIdx.z;
    const float* Xb = X + (size_t)b * CC * NN;
    float* XFb = XF + (size_t)b * CC * NN;
    __shared__ float As[16][68];  // [k][m]
    __shared__ float Bs[16][68];  // [k][n]
    int tid = threadIdx.x;
    int tx = tid & 15, ty = tid >> 4;
    float acc[4][4] = {};
    for (int k0 = 0; k0 < CC; k0 += 16) {
        {
            int m = tid >> 2, kb = (tid & 3) * 4;
            float4 v = *reinterpret_cast<const float4*>(&W[(size_t)(bm + m) * CC + k0 + kb]);
            As[kb + 0][m] = v.x; As[kb + 1][m] = v.y; As[kb + 2][m] = v.z; As[kb + 3][m] = v.w;
            int kk = tid >> 4, n4 = (tid & 15) * 4;
            *reinterpret_cast<float4*>(&Bs[kk][n4]) =
                *reinterpret_cast<const float4*>(&Xb[(size_t)(k0 + kk) * NN + bn + n4]);
        }
        __syncthreads();
#pragma unroll
        for (int kk = 0; kk < 16; ++kk) {
            float4 a4 = *reinterpret_cast<const float4*>(&As[kk][ty * 4]);
            float4 b4 = *reinterpret_cast<const float4*>(&Bs[kk][tx * 4]);
            float a[4] = {a4.x, a4.y, a4.z, a4.w};
            float bv[4] = {b4.x, b4.y, b4.z, b4.w};
#pragma unroll
            for (int i = 0; i < 4; ++i)
#pragma unroll
                for (int j = 0; j < 4; ++j) acc[i][j] = fmaf(a[i], bv[j], acc[i][j]);
        }
        __syncthreads();
    }
#pragma unroll
    for (int i = 0; i < 4; ++i) {
        int o = bm + ty * 4 + i;
        float bi = bias[o];
        float4 v = {acc[i][0] + bi, acc[i][1] + bi, acc[i][2] + bi, acc[i][3] + bi};
        *reinterpret_cast<float4*>(&XFb[(size_t)o * NN + bn + tx * 4]) = v;
    }
}

// z logits + softmax over k + column-sum accumulation
// Z[b,n,k] = softmax_k( sum_c XF[b,c,n] * MU[b,c,k] ); ZSUM[b,k] += sum_n Z
__global__ __launch_bounds__(256) void k_zsoftmax(
    const float* __restrict__ XF, const float* __restrict__ MU,
    float* __restrict__ Z, float* __restrict__ ZSUM) {
    int n0 = blockIdx.x * 64;
    int b  = blockIdx.y;
    const float* XFb = XF + (size_t)b * CC * NN;
    const float* MUb = MU + (size_t)b * CC * KK;
    __shared__ float Xs[16][68];
    __shared__ float Ms[16][68];
    __shared__ float Zs[64][65];
    int tid = threadIdx.x;
    int tx = tid & 15, ty = tid >> 4;
    float acc[4][4] = {};
    for (int c0 = 0; c0 < CC; c0 += 16) {
        {
            int kk = tid >> 4, f4 = (tid & 15) * 4;
            *reinterpret_cast<float4*>(&Xs[kk][f4]) =
                *reinterpret_cast<const float4*>(&XFb[(size_t)(c0 + kk) * NN + n0 + f4]);
            *reinterpret_cast<float4*>(&Ms[kk][f4]) =
                *reinterpret_cast<const float4*>(&MUb[(size_t)(c0 + kk) * KK + f4]);
        }
        __syncthreads();
#pragma unroll
        for (int kk = 0; kk < 16; ++kk) {
            float4 a4 = *reinterpret_cast<const float4*>(&Xs[kk][ty * 4]);
            float4 b4 = *reinterpret_cast<const float4*>(&Ms[kk][tx * 4]);
            float a[4] = {a4.x, a4.y, a4.z, a4.w};
            float bv[4] = {b4.x, b4.y, b4.z, b4.w};
#pragma unroll
            for (int i = 0; i < 4; ++i)
#pragma unroll
                for (int j = 0; j < 4; ++j) acc[i][j] = fmaf(a[i], bv[j], acc[i][j]);
        }
        __syncthreads();
    }
#pragma unroll
    for (int i = 0; i < 4; ++i)
#pragma unroll
        for (int j = 0; j < 4; ++j) Zs[ty * 4 + i][tx * 4 + j] = acc[i][j];
    __syncthreads();
    // softmax over the 64 columns of each row; 4 lanes per row
    int row = tid >> 2, q = tid & 3;
    float m = -1e30f;
    float e[16];
#pragma unroll
    for (int j = 0; j < 16; ++j) m = fmaxf(m, Zs[row][q * 16 + j]);
    m = fmaxf(m, __shfl_xor(m, 1));
    m = fmaxf(m, __shfl_xor(m, 2));
    float s = 0.f;
#pragma unroll
    for (int j = 0; j < 16; ++j) { e[j] = expf(Zs[row][q * 16 + j] - m); s += e[j]; }
    s += __shfl_xor(s, 1);
    s += __shfl_xor(s, 2);
    float inv = 1.0f / s;
    float* Zb = Z + (size_t)b * NN * KK;
#pragma unroll
    for (int j = 0; j < 16; ++j) Zs[row][q * 16 + j] = e[j] * inv;
#pragma unroll
    for (int j = 0; j < 16; j += 4) {
        float4 v = {Zs[row][q * 16 + j], Zs[row][q * 16 + j + 1],
                    Zs[row][q * 16 + j + 2], Zs[row][q * 16 + j + 3]};
        *reinterpret_cast<float4*>(&Zb[(size_t)(n0 + row) * KK + q * 16 + j]) = v;
    }
    __syncthreads();
    if (tid < 64) {
        float cs = 0.f;
        for (int r = 0; r < 64; ++r) cs += Zs[r][tid];
        atomicAdd(&ZSUM[b * KK + tid], cs);
    }
}

// MUACC[b,c,k] = sum_n XF[b,c,n] * Z[b,n,k]
__global__ __launch_bounds__(256) void k_muacc(
    const float* __restrict__ XF, const float* __restrict__ Z,
    float* __restrict__ MUACC) {
    int c0 = blockIdx.x * 32;
    int b  = blockIdx.y;
    const float* XFb = XF + (size_t)b * CC * NN;
    const float* Zb  = Z + (size_t)b * NN * KK;
    __shared__ float Xs[32][68];
    __shared__ float Zs[64][68];
    int tid = threadIdx.x;
    int cy = tid >> 3, kx = tid & 7;
    float acc[8] = {};
    for (int n0 = 0; n0 < NN; n0 += 64) {
        {
            int c = tid >> 3, n8 = (tid & 7) * 8;
            *reinterpret_cast<float4*>(&Xs[c][n8]) =
                *reinterpret_cast<const float4*>(&XFb[(size_t)(c0 + c) * NN + n0 + n8]);
            *reinterpret_cast<float4*>(&Xs[c][n8 + 4]) =
                *reinterpret_cast<const float4*>(&XFb[(size_t)(c0 + c) * NN + n0 + n8 + 4]);
            int j = tid >> 2, k16 = (tid & 3) * 16;
#pragma unroll
            for (int i = 0; i < 16; i += 4)
                *reinterpret_cast<float4*>(&Zs[j][k16 + i]) =
                    *reinterpret_cast<const float4*>(&Zb[(size_t)(n0 + j) * KK + k16 + i]);
        }
        __syncthreads();
#pragma unroll 8
        for (int j = 0; j < 64; ++j) {
            float a = Xs[cy][j];
            float4 z0 = *reinterpret_cast<const float4*>(&Zs[j][kx * 8]);
            float4 z1 = *reinterpret_cast<const float4*>(&Zs[j][kx * 8 + 4]);
            acc[0] = fmaf(a, z0.x, acc[0]); acc[1] = fmaf(a, z0.y, acc[1]);
            acc[2] = fmaf(a, z0.z, acc[2]); acc[3] = fmaf(a, z0.w, acc[3]);
            acc[4] = fmaf(a, z1.x, acc[4]); acc[5] = fmaf(a, z1.y, acc[5]);
            acc[6] = fmaf(a, z1.z, acc[6]); acc[7] = fmaf(a, z1.w, acc[7]);
        }
        __syncthreads();
    }
    float* dst = MUACC + (size_t)b * CC * KK + (size_t)(c0 + cy) * KK + kx * 8;
    float4 o0 = {acc[0], acc[1], acc[2], acc[3]};
    float4 o1 = {acc[4], acc[5], acc[6], acc[7]};
    *reinterpret_cast<float4*>(dst) = o0;
    *reinterpret_cast<float4*>(dst + 4) = o1;
}

// MU[b,c,k] = v / (1e-6 + ||v||_c),  v = MUACC[b,c,k] / (1e-6 + ZSUM[b,k])
__global__ __launch_bounds__(64) void k_munorm(
    const float* __restrict__ MUACC, const float* __restrict__ ZSUM,
    float* __restrict__ MU) {
    int k = blockIdx.x;
    int b = blockIdx.y;
    int lane = threadIdx.x;
    float scale = 1.0f / (1e-6f + ZSUM[b * KK + k]);
    float v[8];
    float ss = 0.f;
#pragma unroll
    for (int i = 0; i < 8; ++i) {
        v[i] = MUACC[(size_t)b * CC * KK + (size_t)(lane + i * 64) * KK + k] * scale;
        ss += v[i] * v[i];
    }
    for (int off = 32; off; off >>= 1) ss += __shfl_xor(ss, off);
    float nrm = 1.0f / (1e-6f + sqrtf(ss));
#pragma unroll
    for (int i = 0; i < 8; ++i)
        MU[(size_t)b * CC * KK + (size_t)(lane + i * 64) * KK + k] = v[i] * nrm;
}

// XR[b,c,n] = relu( sum_k MU[b,c,k] * Z[b,n,k] )
__global__ __launch_bounds__(256) void k_xr(
    const float* __restrict__ MU, const float* __restrict__ Z,
    float* __restrict__ XR) {
    int n0 = blockIdx.x * 64, c0 = blockIdx.y * 64, b = blockIdx.z;
    __shared__ float Ms[64][68];   // [c][k]
    __shared__ float Zt[64][68];   // [k][n]
    int tid = threadIdx.x;
    {
        int row = tid >> 2, k16 = (tid & 3) * 16;
        const float* MUb = MU + (size_t)b * CC * KK;
        const float* Zb  = Z + (size_t)b * NN * KK;
#pragma unroll
        for (int i = 0; i < 16; i += 4) {
            *reinterpret_cast<float4*>(&Ms[row][k16 + i]) =
                *reinterpret_cast<const float4*>(&MUb[(size_t)(c0 + row) * KK + k16 + i]);
            float4 v = *reinterpret_cast<const float4*>(&Zb[(size_t)(n0 + row) * KK + k16 + i]);
            Zt[k16 + i][row] = v.x; Zt[k16 + i + 1][row] = v.y;
            Zt[k16 + i + 2][row] = v.z; Zt[k16 + i + 3][row] = v.w;
        }
    }
    __syncthreads();
    int tx = tid & 15, ty = tid >> 4;
    float acc[4][4] = {};
#pragma unroll 4
    for (int kk = 0; kk < 64; ++kk) {
        float4 b4 = *reinterpret_cast<const float4*>(&Zt[kk][tx * 4]);
        float bv[4] = {b4.x, b4.y, b4.z, b4.w};
        float a[4];
#pragma unroll
        for (int i = 0; i < 4; ++i) a[i] = Ms[ty * 4 + i][kk];
#pragma unroll
        for (int i = 0; i < 4; ++i)
#pragma unroll
            for (int j = 0; j < 4; ++j) acc[i][j] = fmaf(a[i], bv[j], acc[i][j]);
    }
    float* XRb = XR + (size_t)b * CC * NN;
#pragma unroll
    for (int i = 0; i < 4; ++i) {
        float4 v = {fmaxf(acc[i][0], 0.f), fmaxf(acc[i][1], 0.f),
                    fmaxf(acc[i][2], 0.f), fmaxf(acc[i][3], 0.f)};
        *reinterpret_cast<float4*>(&XRb[(size_t)(c0 + ty * 4 + i) * NN + n0 + tx * 4]) = v;
    }
}

// OUT = relu( BN(conv2(XR)) + X )
__global__ __launch_bounds__(256) void k_conv2(
    const float* __restrict__ W, const float* __restrict__ XR,
    const float* __restrict__ X, const float* __restrict__ gamma,
    const float* __restrict__ beta, const float* __restrict__ mean,
    const float* __restrict__ var, float* __restrict__ OUT) {
    int bn = blockIdx.x * 64;
    int bm = blockIdx.y * 64;
    int b  = blockIdx.z;
    const float* XRb = XR + (size_t)b * CC * NN;
    const float* Xb  = X + (size_t)b * CC * NN;
    float* Ob = OUT + (size_t)b * CC * NN;
    __shared__ float As[16][68];
    __shared__ float Bs[16][68];
    int tid = threadIdx.x;
    int tx = tid & 15, ty = tid >> 4;
    float acc[4][4] = {};
    for (int k0 = 0; k0 < CC; k0 += 16) {
        {
            int m = tid >> 2, kb = (tid & 3) * 4;
            float4 v = *reinterpret_cast<const float4*>(&W[(size_t)(bm + m) * CC + k0 + kb]);
            As[kb + 0][m] = v.x; As[kb + 1][m] = v.y; As[kb + 2][m] = v.z; As[kb + 3][m] = v.w;
            int kk = tid >> 4, n4 = (tid & 15) * 4;
            *reinterpret_cast<float4*>(&Bs[kk][n4]) =
                *reinterpret_cast<const float4*>(&XRb[(size_t)(k0 + kk) * NN + bn + n4]);
        }
        __syncthreads();
#pragma unroll
        for (int kk = 0; kk < 16; ++kk) {
            float4 a4 = *reinterpret_cast<const float4*>(&As[kk][ty * 4]);
            float4 b4 = *reinterpret_cast<const float4*>(&Bs[kk][tx * 4]);
            float a[4] = {a4.x, a4.y, a4.z, a4.w};
            float bv[4] = {b4.x, b4.y, b4.z, b4.w};
#pragma unroll
            for (int i = 0; i < 4; ++i)
#pragma unroll
                for (int j = 0; j < 4; ++j) acc[i][j] = fmaf(a[i], bv[j], acc[i][j]);
        }
        __syncthreads();
    }
#pragma unroll
    for (int i = 0; i < 4; ++i) {
        int o = bm + ty * 4 + i;
        float inv = gamma[o] * rsqrtf(var[o] + 1e-5f);
        float sh  = beta[o] - mean[o] * inv;
        float4 xi = *reinterpret_cast<const float4*>(&Xb[(size_t)o * NN + bn + tx * 4]);
        float4 v;
        v.x = fmaxf(acc[i][0] * inv + sh + xi.x, 0.f);
        v.y = fmaxf(acc[i][1] * inv + sh + xi.y, 0.f);
        v.z = fmaxf(acc[i][2] * inv + sh + xi.z, 0.f);
        v.w = fmaxf(acc[i][3] * inv + sh + xi.w, 0.f);
        *reinterpret_cast<float4*>(&Ob[(size_t)o * NN + bn + tx * 4]) = v;
    }
}

extern "C" void kernel_launch(void* const* d_in, const int* in_sizes, int n_in,
                              void* d_out, int out_size, void* d_ws, size_t ws_size,
                              hipStream_t stream) {
    const float* x     = (const float*)d_in[0];
    const float* w1    = (const float*)d_in[1];
    const float* b1    = (const float*)d_in[2];
    const float* mu_in = (const float*)d_in[3];
    const float* w2    = (const float*)d_in[4];
    const float* gamma = (const float*)d_in[5];
    const float* beta  = (const float*)d_in[6];
    const float* mean  = (const float*)d_in[7];
    const float* var   = (const float*)d_in[8];
    float* out = (float*)d_out;
    float* ws  = (float*)d_ws;

    float* xf    = ws + XF_OFF;
    float* z     = ws + Z_OFF;
    float* mu    = ws + MU_OFF;
    float* muacc = ws + MUACC_OFF;
    float* zsum  = ws + ZSUM_OFF;

    hipLaunchKernelGGL(k_mu_bcast, dim3((CC * KK + 255) / 256), dim3(256), 0, stream, mu_in, mu);
    hipLaunchKernelGGL(k_conv1, dim3(NN / 64, CC / 64, BB), dim3(256), 0, stream, w1, b1, x, xf);
    for (int it = 0; it < 3; ++it) {
        hipMemsetAsync(zsum, 0, BB * KK * sizeof(float), stream);
        hipLaunchKernelGGL(k_zsoftmax, dim3(NN / 64, BB), dim3(256), 0, stream, xf, mu, z, zsum);
        hipLaunchKernelGGL(k_muacc, dim3(CC / 32, BB), dim3(256), 0, stream, xf, z, muacc);
        hipLaunchKernelGGL(k_munorm, dim3(KK, BB), dim3(64), 0, stream, muacc, zsum, mu);
    }
    // reuse xf region as XR (xf is dead after the EM loop)
    hipLaunchKernelGGL(k_xr, dim3(NN / 64, CC / 64, BB), dim3(256), 0, stream, mu, z, xf);
    hipLaunchKernelGGL(k_conv2, dim3(NN / 64, CC / 64, BB), dim3(256), 0, stream, w2, xf, x,
                       gamma, beta, mean, var, out);
}

// Round 3
// 1152.272 us; speedup vs baseline: 1.5741x; 1.5741x over previous
//
#include <hip/hip_runtime.h>

typedef __bf16 bf16x8 __attribute__((ext_vector_type(8)));
typedef __bf16 bf16x4 __attribute__((ext_vector_type(4)));
typedef float f32x4 __attribute__((ext_vector_type(4)));

constexpr int CC = 512;   // channels
constexpr int KK = 64;    // bases
constexpr int NN = 4096;  // h*w
constexpr int BB = 16;    // batch

// workspace layout (float units)
constexpr size_t XF_OFF    = 0;                                // fp32 XF [b][c][n]; later reused as bf16 XRT [b][n][c]
constexpr size_t Z_OFF     = (size_t)BB * CC * NN;
constexpr size_t MU_OFF    = Z_OFF + (size_t)BB * NN * KK;
constexpr size_t MUACC_OFF = MU_OFF + (size_t)BB * CC * KK;
constexpr size_t ZSUM_OFF  = MUACC_OFF + (size_t)BB * CC * KK;
constexpr size_t W1BF_OFF  = ZSUM_OFF + (size_t)BB * KK;       // 512*512 bf16 = 131072 float slots
constexpr size_t W2BF_OFF  = W1BF_OFF + (size_t)CC * CC / 2;

// ---------------- fp32 -> bf16 convert (weights) ----------------
__global__ __launch_bounds__(256) void k_cvt(const float* __restrict__ src,
                                             __bf16* __restrict__ dst, int n8) {
    int i = blockIdx.x * 256 + threadIdx.x;
    if (i < n8) {
        const float4* s4 = (const float4*)src;
        float4 a = s4[i * 2], b = s4[i * 2 + 1];
        bf16x8 o;
        o[0] = (__bf16)a.x; o[1] = (__bf16)a.y; o[2] = (__bf16)a.z; o[3] = (__bf16)a.w;
        o[4] = (__bf16)b.x; o[5] = (__bf16)b.y; o[6] = (__bf16)b.z; o[7] = (__bf16)b.w;
        *(bf16x8*)&dst[(size_t)i * 8] = o;
    }
}

// ---------------- X [b][c][n] fp32 -> XT [b][n][c] bf16 ----------------
__global__ __launch_bounds__(256) void k_xpose_cvt(const float* __restrict__ X,
                                                   __bf16* __restrict__ XT) {
    int n0 = blockIdx.x * 64, c0 = blockIdx.y * 64, b = blockIdx.z;
    __shared__ float T[64][65];
    int tid = threadIdx.x;
    const float* Xb = X + (size_t)b * CC * NN;
#pragma unroll
    for (int p = 0; p < 4; ++p) {
        int f4 = tid + p * 256;
        int row = f4 >> 4, col4 = (f4 & 15) * 4;
        float4 v = *(const float4*)&Xb[(size_t)(c0 + row) * NN + n0 + col4];
        T[row][col4 + 0] = v.x; T[row][col4 + 1] = v.y;
        T[row][col4 + 2] = v.z; T[row][col4 + 3] = v.w;
    }
    __syncthreads();
#pragma unroll
    for (int p = 0; p < 2; ++p) {
        int q = tid + p * 256;
        int nl = q >> 3, c8 = (q & 7) * 8;
        bf16x8 o;
#pragma unroll
        for (int j = 0; j < 8; ++j) o[j] = (__bf16)T[c8 + j][nl];
        *(bf16x8*)&XT[((size_t)b * NN + n0 + nl) * CC + c0 + c8] = o;
    }
}

__global__ void k_mu_bcast(const float* __restrict__ mu_in, float* __restrict__ mu) {
    int idx = blockIdx.x * 256 + threadIdx.x;
    if (idx < CC * KK) {
        float v = mu_in[idx];
        for (int b = 0; b < BB; ++b) mu[(size_t)b * CC * KK + idx] = v;
    }
}

// ---------------- bf16 MFMA conv (1x1): Out[b][o][n] from A[o][c], Bt[b][n][c] ----------------
// MODE 0: Out = A*B + bias  (fp32 out)
// MODE 1: Out = relu( (A*B)*inv + sh + Xres )  (BN + residual + relu)
template <int MODE>
__global__ __launch_bounds__(256) void k_conv_mfma(
    const __bf16* __restrict__ A, const __bf16* __restrict__ Bt,
    const float* __restrict__ bias,
    const float* __restrict__ gamma, const float* __restrict__ beta,
    const float* __restrict__ mean, const float* __restrict__ var,
    const float* __restrict__ Xres, float* __restrict__ Out) {
    __shared__ __bf16 As[2][128 * 32];
    __shared__ __bf16 Bs[2][128 * 32];
    __shared__ float sp0[128], sp1[128];
    int tid = threadIdx.x;
    int lane = tid & 63, wave = tid >> 6;
    int wm = wave >> 1, wn = wave & 1;
    int n0 = blockIdx.x * 128, m0 = blockIdx.y * 128, b = blockIdx.z;
    const __bf16* Ab = A + (size_t)m0 * CC;
    const __bf16* Bb = Bt + ((size_t)b * NN + n0) * CC;

    if (MODE == 0) {
        if (tid < 128) sp0[tid] = bias[m0 + tid];
    } else {
        if (tid < 128) {
            float iv = gamma[m0 + tid] * rsqrtf(var[m0 + tid] + 1e-5f);
            sp0[tid] = iv;
            sp1[tid] = beta[m0 + tid] - mean[m0 + tid] * iv;
        }
    }

    f32x4 acc[4][4];
#pragma unroll
    for (int i = 0; i < 4; ++i)
#pragma unroll
        for (int j = 0; j < 4; ++j) acc[i][j] = f32x4{0.f, 0.f, 0.f, 0.f};

    // staging chunk map: 512 16B-chunks per tile, 2 per thread
    int cA0 = tid, cA1 = tid + 256;
    int r0 = cA0 >> 2, k0c = cA0 & 3;
    int r1 = cA1 >> 2, k1c = cA1 & 3;
    int w0 = r0 * 32 + (k0c ^ ((r0 >> 1) & 3)) * 8;   // swizzled LDS element offsets
    int w1 = r1 * 32 + (k1c ^ ((r1 >> 1) & 3)) * 8;

    bf16x8 va0, va1, vb0, vb1;
    // prologue stage kt=0
    va0 = *(const bf16x8*)(Ab + (size_t)r0 * CC + k0c * 8);
    va1 = *(const bf16x8*)(Ab + (size_t)r1 * CC + k1c * 8);
    vb0 = *(const bf16x8*)(Bb + (size_t)r0 * CC + k0c * 8);
    vb1 = *(const bf16x8*)(Bb + (size_t)r1 * CC + k1c * 8);
    *(bf16x8*)&As[0][w0] = va0; *(bf16x8*)&As[0][w1] = va1;
    *(bf16x8*)&Bs[0][w0] = vb0; *(bf16x8*)&Bs[0][w1] = vb1;
    __syncthreads();

    for (int kt = 0; kt < 16; ++kt) {
        int s = kt & 1;
        if (kt < 15) {  // issue next-tile global loads early (latency hides under MFMA)
            const __bf16* Ak = Ab + (kt + 1) * 32;
            const __bf16* Bk = Bb + (kt + 1) * 32;
            va0 = *(const bf16x8*)(Ak + (size_t)r0 * CC + k0c * 8);
            va1 = *(const bf16x8*)(Ak + (size_t)r1 * CC + k1c * 8);
            vb0 = *(const bf16x8*)(Bk + (size_t)r0 * CC + k0c * 8);
            vb1 = *(const bf16x8*)(Bk + (size_t)r1 * CC + k1c * 8);
        }
        bf16x8 af[4], bg[4];
#pragma unroll
        for (int f = 0; f < 4; ++f) {
            int ra = wm * 64 + f * 16 + (lane & 15);
            af[f] = *(const bf16x8*)&As[s][ra * 32 + (((lane >> 4) ^ ((ra >> 1) & 3))) * 8];
            int rb = wn * 64 + f * 16 + (lane & 15);
            bg[f] = *(const bf16x8*)&Bs[s][rb * 32 + (((lane >> 4) ^ ((rb >> 1) & 3))) * 8];
        }
#pragma unroll
        for (int i = 0; i < 4; ++i)
#pragma unroll
            for (int j = 0; j < 4; ++j)
                acc[i][j] = __builtin_amdgcn_mfma_f32_16x16x32_bf16(af[i], bg[j], acc[i][j], 0, 0, 0);
        if (kt < 15) {
            *(bf16x8*)&As[s ^ 1][w0] = va0; *(bf16x8*)&As[s ^ 1][w1] = va1;
            *(bf16x8*)&Bs[s ^ 1][w0] = vb0; *(bf16x8*)&Bs[s ^ 1][w1] = vb1;
        }
        __syncthreads();
    }

    // epilogue: D[row=4*(lane>>4)+r][col=lane&15]
    int gq = lane >> 4, ln = lane & 15;
#pragma unroll
    for (int mf = 0; mf < 4; ++mf) {
#pragma unroll
        for (int r = 0; r < 4; ++r) {
            int o_loc = wm * 64 + mf * 16 + gq * 4 + r;
            size_t orow = ((size_t)b * CC + (m0 + o_loc)) * NN + n0 + wn * 64;
#pragma unroll
            for (int nf = 0; nf < 4; ++nf) {
                int n_loc = nf * 16 + ln;
                float v = acc[mf][nf][r];
                if (MODE == 0) {
                    Out[orow + n_loc] = v + sp0[o_loc];
                } else {
                    float t = v * sp0[o_loc] + sp1[o_loc] + Xres[orow + n_loc];
                    Out[orow + n_loc] = fmaxf(t, 0.f);
                }
            }
        }
    }
}

// ---------------- z logits + softmax over k + column-sum (unchanged fp32) ----------------
__global__ __launch_bounds__(256) void k_zsoftmax(
    const float* __restrict__ XF, const float* __restrict__ MU,
    float* __restrict__ Z, float* __restrict__ ZSUM) {
    int n0 = blockIdx.x * 64;
    int b  = blockIdx.y;
    const float* XFb = XF + (size_t)b * CC * NN;
    const float* MUb = MU + (size_t)b * CC * KK;
    __shared__ float Xs[16][68];
    __shared__ float Ms[16][68];
    __shared__ float Zs[64][65];
    int tid = threadIdx.x;
    int tx = tid & 15, ty = tid >> 4;
    float acc[4][4] = {};
    for (int c0 = 0; c0 < CC; c0 += 16) {
        {
            int kk = tid >> 4, f4 = (tid & 15) * 4;
            *reinterpret_cast<float4*>(&Xs[kk][f4]) =
                *reinterpret_cast<const float4*>(&XFb[(size_t)(c0 + kk) * NN + n0 + f4]);
            *reinterpret_cast<float4*>(&Ms[kk][f4]) =
                *reinterpret_cast<const float4*>(&MUb[(size_t)(c0 + kk) * KK + f4]);
        }
        __syncthreads();
#pragma unroll
        for (int kk = 0; kk < 16; ++kk) {
            float4 a4 = *reinterpret_cast<const float4*>(&Xs[kk][ty * 4]);
            float4 b4 = *reinterpret_cast<const float4*>(&Ms[kk][tx * 4]);
            float a[4] = {a4.x, a4.y, a4.z, a4.w};
            float bv[4] = {b4.x, b4.y, b4.z, b4.w};
#pragma unroll
            for (int i = 0; i < 4; ++i)
#pragma unroll
                for (int j = 0; j < 4; ++j) acc[i][j] = fmaf(a[i], bv[j], acc[i][j]);
        }
        __syncthreads();
    }
#pragma unroll
    for (int i = 0; i < 4; ++i)
#pragma unroll
        for (int j = 0; j < 4; ++j) Zs[ty * 4 + i][tx * 4 + j] = acc[i][j];
    __syncthreads();
    int row = tid >> 2, q = tid & 3;
    float m = -1e30f;
    float e[16];
#pragma unroll
    for (int j = 0; j < 16; ++j) m = fmaxf(m, Zs[row][q * 16 + j]);
    m = fmaxf(m, __shfl_xor(m, 1));
    m = fmaxf(m, __shfl_xor(m, 2));
    float s = 0.f;
#pragma unroll
    for (int j = 0; j < 16; ++j) { e[j] = expf(Zs[row][q * 16 + j] - m); s += e[j]; }
    s += __shfl_xor(s, 1);
    s += __shfl_xor(s, 2);
    float inv = 1.0f / s;
    float* Zb = Z + (size_t)b * NN * KK;
#pragma unroll
    for (int j = 0; j < 16; ++j) Zs[row][q * 16 + j] = e[j] * inv;
#pragma unroll
    for (int j = 0; j < 16; j += 4) {
        float4 v = {Zs[row][q * 16 + j], Zs[row][q * 16 + j + 1],
                    Zs[row][q * 16 + j + 2], Zs[row][q * 16 + j + 3]};
        *reinterpret_cast<float4*>(&Zb[(size_t)(n0 + row) * KK + q * 16 + j]) = v;
    }
    __syncthreads();
    if (tid < 64) {
        float cs = 0.f;
        for (int r = 0; r < 64; ++r) cs += Zs[r][tid];
        atomicAdd(&ZSUM[b * KK + tid], cs);
    }
}

// ---------------- MUACC[b,c,k] = sum_n XF[b,c,n] * Z[b,n,k] (unchanged) ----------------
__global__ __launch_bounds__(256) void k_muacc(
    const float* __restrict__ XF, const float* __restrict__ Z,
    float* __restrict__ MUACC) {
    int c0 = blockIdx.x * 32;
    int b  = blockIdx.y;
    const float* XFb = XF + (size_t)b * CC * NN;
    const float* Zb  = Z + (size_t)b * NN * KK;
    __shared__ float Xs[32][68];
    __shared__ float Zs[64][68];
    int tid = threadIdx.x;
    int cy = tid >> 3, kx = tid & 7;
    float acc[8] = {};
    for (int n0 = 0; n0 < NN; n0 += 64) {
        {
            int c = tid >> 3, n8 = (tid & 7) * 8;
            *reinterpret_cast<float4*>(&Xs[c][n8]) =
                *reinterpret_cast<const float4*>(&XFb[(size_t)(c0 + c) * NN + n0 + n8]);
            *reinterpret_cast<float4*>(&Xs[c][n8 + 4]) =
                *reinterpret_cast<const float4*>(&XFb[(size_t)(c0 + c) * NN + n0 + n8 + 4]);
            int j = tid >> 2, k16 = (tid & 3) * 16;
#pragma unroll
            for (int i = 0; i < 16; i += 4)
                *reinterpret_cast<float4*>(&Zs[j][k16 + i]) =
                    *reinterpret_cast<const float4*>(&Zb[(size_t)(n0 + j) * KK + k16 + i]);
        }
        __syncthreads();
#pragma unroll 8
        for (int j = 0; j < 64; ++j) {
            float a = Xs[cy][j];
            float4 z0 = *reinterpret_cast<const float4*>(&Zs[j][kx * 8]);
            float4 z1 = *reinterpret_cast<const float4*>(&Zs[j][kx * 8 + 4]);
            acc[0] = fmaf(a, z0.x, acc[0]); acc[1] = fmaf(a, z0.y, acc[1]);
            acc[2] = fmaf(a, z0.z, acc[2]); acc[3] = fmaf(a, z0.w, acc[3]);
            acc[4] = fmaf(a, z1.x, acc[4]); acc[5] = fmaf(a, z1.y, acc[5]);
            acc[6] = fmaf(a, z1.z, acc[6]); acc[7] = fmaf(a, z1.w, acc[7]);
        }
        __syncthreads();
    }
    float* dst = MUACC + (size_t)b * CC * KK + (size_t)(c0 + cy) * KK + kx * 8;
    float4 o0 = {acc[0], acc[1], acc[2], acc[3]};
    float4 o1 = {acc[4], acc[5], acc[6], acc[7]};
    *reinterpret_cast<float4*>(dst) = o0;
    *reinterpret_cast<float4*>(dst + 4) = o1;
}

// ---------------- mu normalize (unchanged) ----------------
__global__ __launch_bounds__(64) void k_munorm(
    const float* __restrict__ MUACC, const float* __restrict__ ZSUM,
    float* __restrict__ MU) {
    int k = blockIdx.x;
    int b = blockIdx.y;
    int lane = threadIdx.x;
    float scale = 1.0f / (1e-6f + ZSUM[b * KK + k]);
    float v[8];
    float ss = 0.f;
#pragma unroll
    for (int i = 0; i < 8; ++i) {
        v[i] = MUACC[(size_t)b * CC * KK + (size_t)(lane + i * 64) * KK + k] * scale;
        ss += v[i] * v[i];
    }
    for (int off = 32; off; off >>= 1) ss += __shfl_xor(ss, off);
    float nrm = 1.0f / (1e-6f + sqrtf(ss));
#pragma unroll
    for (int i = 0; i < 8; ++i)
        MU[(size_t)b * CC * KK + (size_t)(lane + i * 64) * KK + k] = v[i] * nrm;
}

// ---------------- XRT[b][n][c] = relu(sum_k Z[b,n,k] * MU[b,c,k]) as bf16 ----------------
__global__ __launch_bounds__(256) void k_xr_t(
    const float* __restrict__ MU, const float* __restrict__ Z,
    __bf16* __restrict__ XRT) {
    int n0 = blockIdx.x * 64, c0 = blockIdx.y * 64, b = blockIdx.z;
    __shared__ float Zt[64][65];
    __shared__ float Mt[64][65];
    const float* Zb = Z + (size_t)b * NN * KK;
    const float* Mb = MU + (size_t)b * CC * KK;
    int tid = threadIdx.x;
#pragma unroll
    for (int p = 0; p < 4; ++p) {
        int f4 = tid + p * 256;
        int rl = f4 >> 4, k4 = (f4 & 15) * 4;
        float4 zv = *(const float4*)&Zb[(size_t)(n0 + rl) * KK + k4];
        Zt[k4 + 0][rl] = zv.x; Zt[k4 + 1][rl] = zv.y;
        Zt[k4 + 2][rl] = zv.z; Zt[k4 + 3][rl] = zv.w;
        float4 mv = *(const float4*)&Mb[(size_t)(c0 + rl) * KK + k4];
        Mt[k4 + 0][rl] = mv.x; Mt[k4 + 1][rl] = mv.y;
        Mt[k4 + 2][rl] = mv.z; Mt[k4 + 3][rl] = mv.w;
    }
    __syncthreads();
    int tx = tid & 15, ty = tid >> 4;
    float acc[4][4] = {};
#pragma unroll 8
    for (int kk = 0; kk < 64; ++kk) {
        float4 z4 = *(const float4*)&Zt[kk][ty * 4];
        float4 m4 = *(const float4*)&Mt[kk][tx * 4];
        float zz[4] = {z4.x, z4.y, z4.z, z4.w};
        float mm[4] = {m4.x, m4.y, m4.z, m4.w};
#pragma unroll
        for (int i = 0; i < 4; ++i)
#pragma unroll
            for (int j = 0; j < 4; ++j) acc[i][j] = fmaf(zz[i], mm[j], acc[i][j]);
    }
#pragma unroll
    for (int i = 0; i < 4; ++i) {
        bf16x4 o;
        o[0] = (__bf16)fmaxf(acc[i][0], 0.f);
        o[1] = (__bf16)fmaxf(acc[i][1], 0.f);
        o[2] = (__bf16)fmaxf(acc[i][2], 0.f);
        o[3] = (__bf16)fmaxf(acc[i][3], 0.f);
        *(bf16x4*)&XRT[((size_t)b * NN + n0 + ty * 4 + i) * CC + c0 + tx * 4] = o;
    }
}

extern "C" void kernel_launch(void* const* d_in, const int* in_sizes, int n_in,
                              void* d_out, int out_size, void* d_ws, size_t ws_size,
                              hipStream_t stream) {
    const float* x     = (const float*)d_in[0];
    const float* w1    = (const float*)d_in[1];
    const float* b1    = (const float*)d_in[2];
    const float* mu_in = (const float*)d_in[3];
    const float* w2    = (const float*)d_in[4];
    const float* gamma = (const float*)d_in[5];
    const float* beta  = (const float*)d_in[6];
    const float* mean  = (const float*)d_in[7];
    const float* var   = (const float*)d_in[8];
    float* out = (float*)d_out;
    float* ws  = (float*)d_ws;

    float* xf    = ws + XF_OFF;
    float* z     = ws + Z_OFF;
    float* mu    = ws + MU_OFF;
    float* muacc = ws + MUACC_OFF;
    float* zsum  = ws + ZSUM_OFF;
    __bf16* w1bf = (__bf16*)(ws + W1BF_OFF);
    __bf16* w2bf = (__bf16*)(ws + W2BF_OFF);
    __bf16* xt   = (__bf16*)d_out;            // X^T bf16 staged in d_out (dead until conv2 writes)
    __bf16* xrt  = (__bf16*)(ws + XF_OFF);    // xr^T bf16 over the dead XF region

    hipLaunchKernelGGL(k_cvt, dim3(128), dim3(256), 0, stream, w1, w1bf, CC * CC / 8);
    hipLaunchKernelGGL(k_cvt, dim3(128), dim3(256), 0, stream, w2, w2bf, CC * CC / 8);
    hipLaunchKernelGGL(k_mu_bcast, dim3((CC * KK + 255) / 256), dim3(256), 0, stream, mu_in, mu);
    hipLaunchKernelGGL(k_xpose_cvt, dim3(NN / 64, CC / 64, BB), dim3(256), 0, stream, x, xt);
    hipLaunchKernelGGL((k_conv_mfma<0>), dim3(NN / 128, CC / 128, BB), dim3(256), 0, stream,
                       w1bf, xt, b1, nullptr, nullptr, nullptr, nullptr, nullptr, xf);
    for (int it = 0; it < 3; ++it) {
        hipMemsetAsync(zsum, 0, BB * KK * sizeof(float), stream);
        hipLaunchKernelGGL(k_zsoftmax, dim3(NN / 64, BB), dim3(256), 0, stream, xf, mu, z, zsum);
        hipLaunchKernelGGL(k_muacc, dim3(CC / 32, BB), dim3(256), 0, stream, xf, z, muacc);
        hipLaunchKernelGGL(k_munorm, dim3(KK, BB), dim3(64), 0, stream, muacc, zsum, mu);
    }
    hipLaunchKernelGGL(k_xr_t, dim3(NN / 64, CC / 64, BB), dim3(256), 0, stream, mu, z, xrt);
    hipLaunchKernelGGL((k_conv_mfma<1>), dim3(NN / 128, CC / 128, BB), dim3(256), 0, stream,
                       w2bf, xrt, nullptr, gamma, beta, mean, var, x, out);
}

// Round 4
// 480.335 us; speedup vs baseline: 3.7761x; 2.3989x over previous
//
#include <hip/hip_runtime.h>

typedef __bf16 bf16x8 __attribute__((ext_vector_type(8)));
typedef float f32x4 __attribute__((ext_vector_type(4)));

constexpr int CC = 512;   // channels
constexpr int KK = 64;    // bases
constexpr int NN = 4096;  // h*w
constexpr int BB = 16;    // batch

// workspace layout (float units). Total = 39,060,480 floats (== proven round-3 usage)
constexpr size_t R1_OFF    = 0;                     // XT bf16 [b][n][c], later XFC bf16 [b][c][n]
constexpr size_t R2_OFF    = 16777216;              // XFT bf16 [b][n][c], later XRT bf16 [b][n][c]
constexpr size_t Z_OFF     = 33554432;              // Z  bf16 [b][n][k]
constexpr size_t ZT_OFF    = 35651584;              // ZT bf16 [b][k][n]
constexpr size_t MUACC_OFF = 37748736;              // fp32 [b][c][k]
constexpr size_t ZSUM_OFF  = 38273024;              // fp32 [b][k]
constexpr size_t MUBF_OFF  = 38274048;              // bf16 [b][c][k]
constexpr size_t MUTBF_OFF = 38536192;              // bf16 [b][k][c]
constexpr size_t W1BF_OFF  = 38798336;              // bf16 [o][c]
constexpr size_t W2BF_OFF  = 38929408;              // bf16 [o][c]

// ---------------- fp32 -> bf16 convert (weights) ----------------
__global__ __launch_bounds__(256) void k_cvt(const float* __restrict__ src,
                                             __bf16* __restrict__ dst, int n8) {
    int i = blockIdx.x * 256 + threadIdx.x;
    if (i < n8) {
        const float4* s4 = (const float4*)src;
        float4 a = s4[i * 2], b = s4[i * 2 + 1];
        bf16x8 o;
        o[0] = (__bf16)a.x; o[1] = (__bf16)a.y; o[2] = (__bf16)a.z; o[3] = (__bf16)a.w;
        o[4] = (__bf16)b.x; o[5] = (__bf16)b.y; o[6] = (__bf16)b.z; o[7] = (__bf16)b.w;
        *(bf16x8*)&dst[(size_t)i * 8] = o;
    }
}

// ---------------- initial mu broadcast to both bf16 layouts ----------------
__global__ __launch_bounds__(256) void k_mu_bcast_bf(const float* __restrict__ mu_in,
                                                     __bf16* __restrict__ mu_bf,
                                                     __bf16* __restrict__ muT_bf) {
    int idx = blockIdx.x * 256 + threadIdx.x;
    if (idx < CC * KK) {
        int c = idx >> 6, k = idx & 63;
        __bf16 v = (__bf16)mu_in[idx];
        for (int b = 0; b < BB; ++b) {
            mu_bf[(size_t)b * CC * KK + idx] = v;
            muT_bf[((size_t)b * KK + k) * CC + c] = v;
        }
    }
}

// ---------------- X [b][c][n] fp32 -> XT [b][n][c] bf16 ----------------
__global__ __launch_bounds__(256) void k_xpose_cvt(const float* __restrict__ X,
                                                   __bf16* __restrict__ XT) {
    int n0 = blockIdx.x * 64, c0 = blockIdx.y * 64, b = blockIdx.z;
    __shared__ float T[64][65];
    int tid = threadIdx.x;
    const float* Xb = X + (size_t)b * CC * NN;
#pragma unroll
    for (int p = 0; p < 4; ++p) {
        int f4 = tid + p * 256;
        int row = f4 >> 4, col4 = (f4 & 15) * 4;
        float4 v = *(const float4*)&Xb[(size_t)(c0 + row) * NN + n0 + col4];
        T[row][col4 + 0] = v.x; T[row][col4 + 1] = v.y;
        T[row][col4 + 2] = v.z; T[row][col4 + 3] = v.w;
    }
    __syncthreads();
#pragma unroll
    for (int p = 0; p < 2; ++p) {
        int q = tid + p * 256;
        int nl = q >> 3, c8 = (q & 7) * 8;
        bf16x8 o;
#pragma unroll
        for (int j = 0; j < 8; ++j) o[j] = (__bf16)T[c8 + j][nl];
        *(bf16x8*)&XT[((size_t)b * NN + n0 + nl) * CC + c0 + c8] = o;
    }
}

// ---------------- XFT [b][n][c] bf16 -> XFC [b][c][n] bf16 ----------------
__global__ __launch_bounds__(256) void k_xftrans(const __bf16* __restrict__ XFT,
                                                 __bf16* __restrict__ XFC) {
    int n0 = blockIdx.x * 64, c0 = blockIdx.y * 64, b = blockIdx.z;
    __shared__ __bf16 T[64][66];   // 66 -> 33-bank row stride (odd), 2-way max conflict
    int tid = threadIdx.x;
#pragma unroll
    for (int p = 0; p < 2; ++p) {
        int idx = tid + p * 256;
        int row = idx >> 3, c8 = (idx & 7) * 8;
        bf16x8 v = *(const bf16x8*)&XFT[((size_t)b * NN + n0 + row) * CC + c0 + c8];
#pragma unroll
        for (int j = 0; j < 8; ++j) T[row][c8 + j] = v[j];
    }
    __syncthreads();
#pragma unroll
    for (int p = 0; p < 2; ++p) {
        int idx = tid + p * 256;
        int crow = idx >> 3, n8 = (idx & 7) * 8;
        bf16x8 o;
#pragma unroll
        for (int j = 0; j < 8; ++j) o[j] = T[n8 + j][crow];
        *(bf16x8*)&XFC[((size_t)b * CC + c0 + crow) * NN + n0 + n8] = o;
    }
}

// ---------------- conv1: XFT[b][n][o] = bf16( XT[b][n][:]·W1[o][:] + b1[o] ) ----------------
__global__ __launch_bounds__(256) void k_conv1_mfma(
    const __bf16* __restrict__ XT, const __bf16* __restrict__ W1,
    const float* __restrict__ bias, __bf16* __restrict__ XFT) {
    __shared__ __bf16 As[2][128 * 32];
    __shared__ __bf16 Bs[2][128 * 32];
    __shared__ float sbias[128];
    int tid = threadIdx.x;
    int lane = tid & 63, wave = tid >> 6;
    int wm = wave >> 1, wn = wave & 1;
    int o0 = blockIdx.x * 128, n0 = blockIdx.y * 128, b = blockIdx.z;
    const __bf16* Ab = XT + ((size_t)b * NN + n0) * CC;
    const __bf16* Bb = W1 + (size_t)o0 * CC;
    if (tid < 128) sbias[tid] = bias[o0 + tid];

    f32x4 acc[4][4];
#pragma unroll
    for (int i = 0; i < 4; ++i)
#pragma unroll
        for (int j = 0; j < 4; ++j) acc[i][j] = f32x4{0.f, 0.f, 0.f, 0.f};

    int r0 = tid >> 2, k0c = tid & 3;
    int r1 = (tid + 256) >> 2, k1c = tid & 3;
    int w0 = r0 * 32 + (k0c ^ ((r0 >> 1) & 3)) * 8;
    int w1 = r1 * 32 + (k1c ^ ((r1 >> 1) & 3)) * 8;

    bf16x8 va0, va1, vb0, vb1;
    va0 = *(const bf16x8*)(Ab + (size_t)r0 * CC + k0c * 8);
    va1 = *(const bf16x8*)(Ab + (size_t)r1 * CC + k1c * 8);
    vb0 = *(const bf16x8*)(Bb + (size_t)r0 * CC + k0c * 8);
    vb1 = *(const bf16x8*)(Bb + (size_t)r1 * CC + k1c * 8);
    *(bf16x8*)&As[0][w0] = va0; *(bf16x8*)&As[0][w1] = va1;
    *(bf16x8*)&Bs[0][w0] = vb0; *(bf16x8*)&Bs[0][w1] = vb1;
    __syncthreads();

    for (int kt = 0; kt < 16; ++kt) {
        int s = kt & 1;
        if (kt < 15) {
            const __bf16* Ak = Ab + (kt + 1) * 32;
            const __bf16* Bk = Bb + (kt + 1) * 32;
            va0 = *(const bf16x8*)(Ak + (size_t)r0 * CC + k0c * 8);
            va1 = *(const bf16x8*)(Ak + (size_t)r1 * CC + k1c * 8);
            vb0 = *(const bf16x8*)(Bk + (size_t)r0 * CC + k0c * 8);
            vb1 = *(const bf16x8*)(Bk + (size_t)r1 * CC + k1c * 8);
        }
        bf16x8 af[4], bg[4];
#pragma unroll
        for (int f = 0; f < 4; ++f) {
            int ra = wm * 64 + f * 16 + (lane & 15);
            af[f] = *(const bf16x8*)&As[s][ra * 32 + (((lane >> 4) ^ ((ra >> 1) & 3))) * 8];
            int rb = wn * 64 + f * 16 + (lane & 15);
            bg[f] = *(const bf16x8*)&Bs[s][rb * 32 + (((lane >> 4) ^ ((rb >> 1) & 3))) * 8];
        }
#pragma unroll
        for (int i = 0; i < 4; ++i)
#pragma unroll
            for (int j = 0; j < 4; ++j)
                acc[i][j] = __builtin_amdgcn_mfma_f32_16x16x32_bf16(af[i], bg[j], acc[i][j], 0, 0, 0);
        if (kt < 15) {
            *(bf16x8*)&As[s ^ 1][w0] = va0; *(bf16x8*)&As[s ^ 1][w1] = va1;
            *(bf16x8*)&Bs[s ^ 1][w0] = vb0; *(bf16x8*)&Bs[s ^ 1][w1] = vb1;
        }
        __syncthreads();
    }

    int gq = lane >> 4, ln = lane & 15;
#pragma unroll
    for (int mf = 0; mf < 4; ++mf) {
#pragma unroll
        for (int r = 0; r < 4; ++r) {
            int n_loc = wm * 64 + mf * 16 + gq * 4 + r;
            size_t orow = ((size_t)b * NN + n0 + n_loc) * CC + o0 + wn * 64;
#pragma unroll
            for (int nf = 0; nf < 4; ++nf) {
                int o_loc = wn * 64 + nf * 16 + ln;
                XFT[orow + nf * 16 + ln] = (__bf16)(acc[mf][nf][r] + sbias[o_loc]);
            }
        }
    }
}

// ---------------- conv2: OUT = relu( BN(W2·XR) + X ), B-operand XRT[b][n][c] bf16 ----------------
__global__ __launch_bounds__(256) void k_conv2_mfma(
    const __bf16* __restrict__ A, const __bf16* __restrict__ Bt,
    const float* __restrict__ gamma, const float* __restrict__ beta,
    const float* __restrict__ mean, const float* __restrict__ var,
    const float* __restrict__ Xres, float* __restrict__ Out) {
    __shared__ __bf16 As[2][128 * 32];
    __shared__ __bf16 Bs[2][128 * 32];
    __shared__ float sp0[128], sp1[128];
    int tid = threadIdx.x;
    int lane = tid & 63, wave = tid >> 6;
    int wm = wave >> 1, wn = wave & 1;
    int n0 = blockIdx.x * 128, m0 = blockIdx.y * 128, b = blockIdx.z;
    const __bf16* Ab = A + (size_t)m0 * CC;
    const __bf16* Bb = Bt + ((size_t)b * NN + n0) * CC;
    if (tid < 128) {
        float iv = gamma[m0 + tid] * rsqrtf(var[m0 + tid] + 1e-5f);
        sp0[tid] = iv;
        sp1[tid] = beta[m0 + tid] - mean[m0 + tid] * iv;
    }

    f32x4 acc[4][4];
#pragma unroll
    for (int i = 0; i < 4; ++i)
#pragma unroll
        for (int j = 0; j < 4; ++j) acc[i][j] = f32x4{0.f, 0.f, 0.f, 0.f};

    int r0 = tid >> 2, k0c = tid & 3;
    int r1 = (tid + 256) >> 2, k1c = tid & 3;
    int w0 = r0 * 32 + (k0c ^ ((r0 >> 1) & 3)) * 8;
    int w1 = r1 * 32 + (k1c ^ ((r1 >> 1) & 3)) * 8;

    bf16x8 va0, va1, vb0, vb1;
    va0 = *(const bf16x8*)(Ab + (size_t)r0 * CC + k0c * 8);
    va1 = *(const bf16x8*)(Ab + (size_t)r1 * CC + k1c * 8);
    vb0 = *(const bf16x8*)(Bb + (size_t)r0 * CC + k0c * 8);
    vb1 = *(const bf16x8*)(Bb + (size_t)r1 * CC + k1c * 8);
    *(bf16x8*)&As[0][w0] = va0; *(bf16x8*)&As[0][w1] = va1;
    *(bf16x8*)&Bs[0][w0] = vb0; *(bf16x8*)&Bs[0][w1] = vb1;
    __syncthreads();

    for (int kt = 0; kt < 16; ++kt) {
        int s = kt & 1;
        if (kt < 15) {
            const __bf16* Ak = Ab + (kt + 1) * 32;
            const __bf16* Bk = Bb + (kt + 1) * 32;
            va0 = *(const bf16x8*)(Ak + (size_t)r0 * CC + k0c * 8);
            va1 = *(const bf16x8*)(Ak + (size_t)r1 * CC + k1c * 8);
            vb0 = *(const bf16x8*)(Bk + (size_t)r0 * CC + k0c * 8);
            vb1 = *(const bf16x8*)(Bk + (size_t)r1 * CC + k1c * 8);
        }
        bf16x8 af[4], bg[4];
#pragma unroll
        for (int f = 0; f < 4; ++f) {
            int ra = wm * 64 + f * 16 + (lane & 15);
            af[f] = *(const bf16x8*)&As[s][ra * 32 + (((lane >> 4) ^ ((ra >> 1) & 3))) * 8];
            int rb = wn * 64 + f * 16 + (lane & 15);
            bg[f] = *(const bf16x8*)&Bs[s][rb * 32 + (((lane >> 4) ^ ((rb >> 1) & 3))) * 8];
        }
#pragma unroll
        for (int i = 0; i < 4; ++i)
#pragma unroll
            for (int j = 0; j < 4; ++j)
                acc[i][j] = __builtin_amdgcn_mfma_f32_16x16x32_bf16(af[i], bg[j], acc[i][j], 0, 0, 0);
        if (kt < 15) {
            *(bf16x8*)&As[s ^ 1][w0] = va0; *(bf16x8*)&As[s ^ 1][w1] = va1;
            *(bf16x8*)&Bs[s ^ 1][w0] = vb0; *(bf16x8*)&Bs[s ^ 1][w1] = vb1;
        }
        __syncthreads();
    }

    int gq = lane >> 4, ln = lane & 15;
#pragma unroll
    for (int mf = 0; mf < 4; ++mf) {
#pragma unroll
        for (int r = 0; r < 4; ++r) {
            int o_loc = wm * 64 + mf * 16 + gq * 4 + r;
            size_t orow = ((size_t)b * CC + (m0 + o_loc)) * NN + n0 + wn * 64;
#pragma unroll
            for (int nf = 0; nf < 4; ++nf) {
                int n_loc = nf * 16 + ln;
                float t = acc[mf][nf][r] * sp0[o_loc] + sp1[o_loc] + Xres[orow + n_loc];
                Out[orow + n_loc] = fmaxf(t, 0.f);
            }
        }
    }
}

// ---------------- zsoftmax: logits MFMA + in-register softmax + Z/ZT/zsum ----------------
// tile 128 n-rows x 64 k-cols; 4 waves stacked on n (32 rows each, full k-range per wave)
__global__ __launch_bounds__(256) void k_zsoftmax_mfma(
    const __bf16* __restrict__ XFT, const __bf16* __restrict__ MUT,
    __bf16* __restrict__ Z, __bf16* __restrict__ ZT, float* __restrict__ ZSUM) {
    __shared__ __bf16 As[2][128 * 32];
    __shared__ __bf16 Bs[2][64 * 32];
    int tid = threadIdx.x;
    int lane = tid & 63, wave = tid >> 6;
    int n0 = blockIdx.x * 128, b = blockIdx.y;
    const __bf16* Ab = XFT + ((size_t)b * NN + n0) * CC;
    const __bf16* Bb = MUT + (size_t)b * KK * CC;

    f32x4 acc[2][4];
#pragma unroll
    for (int i = 0; i < 2; ++i)
#pragma unroll
        for (int j = 0; j < 4; ++j) acc[i][j] = f32x4{0.f, 0.f, 0.f, 0.f};

    int r0 = tid >> 2, k0c = tid & 3;
    int r1 = (tid + 256) >> 2, k1c = tid & 3;
    int w0 = r0 * 32 + (k0c ^ ((r0 >> 1) & 3)) * 8;
    int w1 = r1 * 32 + (k1c ^ ((r1 >> 1) & 3)) * 8;
    int rB = tid >> 2, kB = tid & 3;
    int wB = rB * 32 + (kB ^ ((rB >> 1) & 3)) * 8;

    bf16x8 va0, va1, vb0;
    va0 = *(const bf16x8*)(Ab + (size_t)r0 * CC + k0c * 8);
    va1 = *(const bf16x8*)(Ab + (size_t)r1 * CC + k1c * 8);
    vb0 = *(const bf16x8*)(Bb + (size_t)rB * CC + kB * 8);
    *(bf16x8*)&As[0][w0] = va0; *(bf16x8*)&As[0][w1] = va1;
    *(bf16x8*)&Bs[0][wB] = vb0;
    __syncthreads();

    for (int kt = 0; kt < 16; ++kt) {
        int s = kt & 1;
        if (kt < 15) {
            const __bf16* Ak = Ab + (kt + 1) * 32;
            const __bf16* Bk = Bb + (kt + 1) * 32;
            va0 = *(const bf16x8*)(Ak + (size_t)r0 * CC + k0c * 8);
            va1 = *(const bf16x8*)(Ak + (size_t)r1 * CC + k1c * 8);
            vb0 = *(const bf16x8*)(Bk + (size_t)rB * CC + kB * 8);
        }
        bf16x8 af[2], bg[4];
#pragma unroll
        for (int f = 0; f < 2; ++f) {
            int ra = wave * 32 + f * 16 + (lane & 15);
            af[f] = *(const bf16x8*)&As[s][ra * 32 + (((lane >> 4) ^ ((ra >> 1) & 3))) * 8];
        }
#pragma unroll
        for (int f = 0; f < 4; ++f) {
            int rb = f * 16 + (lane & 15);
            bg[f] = *(const bf16x8*)&Bs[s][rb * 32 + (((lane >> 4) ^ ((rb >> 1) & 3))) * 8];
        }
#pragma unroll
        for (int i = 0; i < 2; ++i)
#pragma unroll
            for (int j = 0; j < 4; ++j)
                acc[i][j] = __builtin_amdgcn_mfma_f32_16x16x32_bf16(af[i], bg[j], acc[i][j], 0, 0, 0);
        if (kt < 15) {
            *(bf16x8*)&As[s ^ 1][w0] = va0; *(bf16x8*)&As[s ^ 1][w1] = va1;
            *(bf16x8*)&Bs[s ^ 1][wB] = vb0;
        }
        __syncthreads();
    }

    // softmax over k=64 per row; row owned by 16 lanes (same lane>>4 group)
    int gq = lane >> 4, ln = lane & 15;
    float zp[4] = {0.f, 0.f, 0.f, 0.f};
#pragma unroll
    for (int mf = 0; mf < 2; ++mf) {
#pragma unroll
        for (int r = 0; r < 4; ++r) {
            float mx = fmaxf(fmaxf(acc[mf][0][r], acc[mf][1][r]),
                             fmaxf(acc[mf][2][r], acc[mf][3][r]));
            mx = fmaxf(mx, __shfl_xor(mx, 1));
            mx = fmaxf(mx, __shfl_xor(mx, 2));
            mx = fmaxf(mx, __shfl_xor(mx, 4));
            mx = fmaxf(mx, __shfl_xor(mx, 8));
            float e[4];
            float ssum = 0.f;
#pragma unroll
            for (int nf = 0; nf < 4; ++nf) { e[nf] = expf(acc[mf][nf][r] - mx); ssum += e[nf]; }
            ssum += __shfl_xor(ssum, 1);
            ssum += __shfl_xor(ssum, 2);
            ssum += __shfl_xor(ssum, 4);
            ssum += __shfl_xor(ssum, 8);
            float inv = 1.0f / ssum;
            int n_loc = wave * 32 + mf * 16 + gq * 4 + r;
            size_t zrow = ((size_t)b * NN + n0 + n_loc) * KK;
#pragma unroll
            for (int nf = 0; nf < 4; ++nf) {
                float zv = e[nf] * inv;
                zp[nf] += zv;
                int k = nf * 16 + ln;
                Z[zrow + k] = (__bf16)zv;
                ZT[((size_t)b * KK + k) * NN + n0 + n_loc] = (__bf16)zv;
            }
        }
    }
#pragma unroll
    for (int nf = 0; nf < 4; ++nf) {
        float t = zp[nf];
        t += __shfl_xor(t, 16);
        t += __shfl_xor(t, 32);
        if (lane < 16) atomicAdd(&ZSUM[b * KK + nf * 16 + ln], t);
    }
}

// ---------------- muacc: MUACC[c][k] += sum_n XFC[c][n]·ZT[k][n], split-K over n ----------------
// tile 128c x 64k, waves 2x2 (wave 64c x 32k); 8 n-splits of 512
__global__ __launch_bounds__(256) void k_muacc_mfma(
    const __bf16* __restrict__ XFC, const __bf16* __restrict__ ZT,
    float* __restrict__ MUACC) {
    __shared__ __bf16 As[2][128 * 32];
    __shared__ __bf16 Bs[2][64 * 32];
    int tid = threadIdx.x;
    int lane = tid & 63, wave = tid >> 6;
    int wm = wave >> 1, wn = wave & 1;
    int c0 = (blockIdx.x & 3) * 128, sp = blockIdx.x >> 2, b = blockIdx.y;
    size_t nbase = (size_t)sp * 512;
    const __bf16* Ab = XFC + ((size_t)b * CC + c0) * NN + nbase;
    const __bf16* Bb = ZT + (size_t)b * KK * NN + nbase;

    f32x4 acc[4][2];
#pragma unroll
    for (int i = 0; i < 4; ++i)
#pragma unroll
        for (int j = 0; j < 2; ++j) acc[i][j] = f32x4{0.f, 0.f, 0.f, 0.f};

    int r0 = tid >> 2, k0c = tid & 3;
    int r1 = (tid + 256) >> 2, k1c = tid & 3;
    int w0 = r0 * 32 + (k0c ^ ((r0 >> 1) & 3)) * 8;
    int w1 = r1 * 32 + (k1c ^ ((r1 >> 1) & 3)) * 8;
    int rB = tid >> 2, kB = tid & 3;
    int wB = rB * 32 + (kB ^ ((rB >> 1) & 3)) * 8;

    bf16x8 va0, va1, vb0;
    va0 = *(const bf16x8*)(Ab + (size_t)r0 * NN + k0c * 8);
    va1 = *(const bf16x8*)(Ab + (size_t)r1 * NN + k1c * 8);
    vb0 = *(const bf16x8*)(Bb + (size_t)rB * NN + kB * 8);
    *(bf16x8*)&As[0][w0] = va0; *(bf16x8*)&As[0][w1] = va1;
    *(bf16x8*)&Bs[0][wB] = vb0;
    __syncthreads();

    for (int kt = 0; kt < 16; ++kt) {
        int s = kt & 1;
        if (kt < 15) {
            const __bf16* Ak = Ab + (kt + 1) * 32;
            const __bf16* Bk = Bb + (kt + 1) * 32;
            va0 = *(const bf16x8*)(Ak + (size_t)r0 * NN + k0c * 8);
            va1 = *(const bf16x8*)(Ak + (size_t)r1 * NN + k1c * 8);
            vb0 = *(const bf16x8*)(Bk + (size_t)rB * NN + kB * 8);
        }
        bf16x8 af[4], bg[2];
#pragma unroll
        for (int f = 0; f < 4; ++f) {
            int ra = wm * 64 + f * 16 + (lane & 15);
            af[f] = *(const bf16x8*)&As[s][ra * 32 + (((lane >> 4) ^ ((ra >> 1) & 3))) * 8];
        }
#pragma unroll
        for (int f = 0; f < 2; ++f) {
            int rb = wn * 32 + f * 16 + (lane & 15);
            bg[f] = *(const bf16x8*)&Bs[s][rb * 32 + (((lane >> 4) ^ ((rb >> 1) & 3))) * 8];
        }
#pragma unroll
        for (int i = 0; i < 4; ++i)
#pragma unroll
            for (int j = 0; j < 2; ++j)
                acc[i][j] = __builtin_amdgcn_mfma_f32_16x16x32_bf16(af[i], bg[j], acc[i][j], 0, 0, 0);
        if (kt < 15) {
            *(bf16x8*)&As[s ^ 1][w0] = va0; *(bf16x8*)&As[s ^ 1][w1] = va1;
            *(bf16x8*)&Bs[s ^ 1][wB] = vb0;
        }
        __syncthreads();
    }

    int gq = lane >> 4, ln = lane & 15;
#pragma unroll
    for (int mf = 0; mf < 4; ++mf) {
#pragma unroll
        for (int r = 0; r < 4; ++r) {
            int row = wm * 64 + mf * 16 + gq * 4 + r;
#pragma unroll
            for (int nf = 0; nf < 2; ++nf) {
                int col = wn * 32 + nf * 16 + ln;
                atomicAdd(&MUACC[((size_t)b * CC + c0 + row) * KK + col], acc[mf][nf][r]);
            }
        }
    }
}

// ---------------- munorm -> bf16 mu (both layouts) ----------------
__global__ __launch_bounds__(64) void k_munorm_bf(
    const float* __restrict__ MUACC, const float* __restrict__ ZSUM,
    __bf16* __restrict__ mu_bf, __bf16* __restrict__ muT_bf) {
    int k = blockIdx.x;
    int b = blockIdx.y;
    int lane = threadIdx.x;
    float scale = 1.0f / (1e-6f + ZSUM[b * KK + k]);
    float v[8];
    float ss = 0.f;
#pragma unroll
    for (int i = 0; i < 8; ++i) {
        v[i] = MUACC[(size_t)b * CC * KK + (size_t)(lane + i * 64) * KK + k] * scale;
        ss += v[i] * v[i];
    }
    for (int off = 32; off; off >>= 1) ss += __shfl_xor(ss, off);
    float nrm = 1.0f / (1e-6f + sqrtf(ss));
#pragma unroll
    for (int i = 0; i < 8; ++i) {
        int c = lane + i * 64;
        __bf16 o = (__bf16)(v[i] * nrm);
        mu_bf[((size_t)b * CC + c) * KK + k] = o;
        muT_bf[((size_t)b * KK + k) * CC + c] = o;
    }
}

// ---------------- xr: XRT[b][n][c] = bf16(relu( sum_k Z[n][k]·mu[c][k] )), K=64 ----------------
// tile 128n x 128c, waves 2x2, single-stage K
__global__ __launch_bounds__(256) void k_xr_mfma(
    const __bf16* __restrict__ Zm, const __bf16* __restrict__ MUB,
    __bf16* __restrict__ XRT) {
    __shared__ __bf16 As[128 * 64];
    __shared__ __bf16 Bs[128 * 64];
    int tid = threadIdx.x;
    int lane = tid & 63, wave = tid >> 6;
    int wm = wave >> 1, wn = wave & 1;
    int n0 = blockIdx.x * 128, c0 = blockIdx.y * 128, b = blockIdx.z;
    const __bf16* Ab = Zm + ((size_t)b * NN + n0) * KK;
    const __bf16* Bb = MUB + ((size_t)b * CC + c0) * KK;
#pragma unroll
    for (int p = 0; p < 4; ++p) {
        int idx = tid + p * 256;
        int r = idx >> 3, ch = idx & 7;
        int woff = r * 64 + ((ch ^ (r & 7)) * 8);
        *(bf16x8*)&As[woff] = *(const bf16x8*)(Ab + (size_t)r * KK + ch * 8);
        *(bf16x8*)&Bs[woff] = *(const bf16x8*)(Bb + (size_t)r * KK + ch * 8);
    }
    __syncthreads();

    f32x4 acc[4][4];
#pragma unroll
    for (int i = 0; i < 4; ++i)
#pragma unroll
        for (int j = 0; j < 4; ++j) acc[i][j] = f32x4{0.f, 0.f, 0.f, 0.f};

    int gq = lane >> 4, ln = lane & 15;
#pragma unroll
    for (int ks = 0; ks < 2; ++ks) {
        bf16x8 af[4], bg[4];
#pragma unroll
        for (int f = 0; f < 4; ++f) {
            int ra = wm * 64 + f * 16 + ln;
            af[f] = *(const bf16x8*)&As[ra * 64 + (((ks * 4 + gq) ^ (ra & 7))) * 8];
            int rb = wn * 64 + f * 16 + ln;
            bg[f] = *(const bf16x8*)&Bs[rb * 64 + (((ks * 4 + gq) ^ (rb & 7))) * 8];
        }
#pragma unroll
        for (int i = 0; i < 4; ++i)
#pragma unroll
            for (int j = 0; j < 4; ++j)
                acc[i][j] = __builtin_amdgcn_mfma_f32_16x16x32_bf16(af[i], bg[j], acc[i][j], 0, 0, 0);
    }

#pragma unroll
    for (int mf = 0; mf < 4; ++mf) {
#pragma unroll
        for (int r = 0; r < 4; ++r) {
            int n_loc = wm * 64 + mf * 16 + gq * 4 + r;
            size_t orow = ((size_t)b * NN + n0 + n_loc) * CC + c0 + wn * 64;
#pragma unroll
            for (int nf = 0; nf < 4; ++nf) {
                XRT[orow + nf * 16 + ln] = (__bf16)fmaxf(acc[mf][nf][r], 0.f);
            }
        }
    }
}

extern "C" void kernel_launch(void* const* d_in, const int* in_sizes, int n_in,
                              void* d_out, int out_size, void* d_ws, size_t ws_size,
                              hipStream_t stream) {
    const float* x     = (const float*)d_in[0];
    const float* w1    = (const float*)d_in[1];
    const float* b1    = (const float*)d_in[2];
    const float* mu_in = (const float*)d_in[3];
    const float* w2    = (const float*)d_in[4];
    const float* gamma = (const float*)d_in[5];
    const float* beta  = (const float*)d_in[6];
    const float* mean  = (const float*)d_in[7];
    const float* var   = (const float*)d_in[8];
    float* out = (float*)d_out;
    float* ws  = (float*)d_ws;

    __bf16* xt    = (__bf16*)(ws + R1_OFF);    // region 1: XT, later XFC
    __bf16* xfc   = (__bf16*)(ws + R1_OFF);
    __bf16* xft   = (__bf16*)(ws + R2_OFF);    // region 2: XFT, later XRT
    __bf16* xrt   = (__bf16*)(ws + R2_OFF);
    __bf16* zbf   = (__bf16*)(ws + Z_OFF);
    __bf16* ztbf  = (__bf16*)(ws + ZT_OFF);
    float*  muacc = ws + MUACC_OFF;
    float*  zsum  = ws + ZSUM_OFF;
    __bf16* mu_bf = (__bf16*)(ws + MUBF_OFF);
    __bf16* muT_bf= (__bf16*)(ws + MUTBF_OFF);
    __bf16* w1bf  = (__bf16*)(ws + W1BF_OFF);
    __bf16* w2bf  = (__bf16*)(ws + W2BF_OFF);

    hipLaunchKernelGGL(k_cvt, dim3(128), dim3(256), 0, stream, w1, w1bf, CC * CC / 8);
    hipLaunchKernelGGL(k_cvt, dim3(128), dim3(256), 0, stream, w2, w2bf, CC * CC / 8);
    hipLaunchKernelGGL(k_mu_bcast_bf, dim3(128), dim3(256), 0, stream, mu_in, mu_bf, muT_bf);
    hipLaunchKernelGGL(k_xpose_cvt, dim3(NN / 64, CC / 64, BB), dim3(256), 0, stream, x, xt);
    hipLaunchKernelGGL(k_conv1_mfma, dim3(CC / 128, NN / 128, BB), dim3(256), 0, stream,
                       xt, w1bf, b1, xft);
    hipLaunchKernelGGL(k_xftrans, dim3(NN / 64, CC / 64, BB), dim3(256), 0, stream, xft, xfc);
    for (int it = 0; it < 3; ++it) {
        // MUACC and ZSUM are contiguous: one memset clears both
        hipMemsetAsync(muacc, 0, (size_t)(BB * CC * KK + BB * KK) * sizeof(float), stream);
        hipLaunchKernelGGL(k_zsoftmax_mfma, dim3(NN / 128, BB), dim3(256), 0, stream,
                           xft, muT_bf, zbf, ztbf, zsum);
        hipLaunchKernelGGL(k_muacc_mfma, dim3(32, BB), dim3(256), 0, stream, xfc, ztbf, muacc);
        hipLaunchKernelGGL(k_munorm_bf, dim3(KK, BB), dim3(64), 0, stream, muacc, zsum,
                           mu_bf, muT_bf);
    }
    hipLaunchKernelGGL(k_xr_mfma, dim3(NN / 128, CC / 128, BB), dim3(256), 0, stream,
                       zbf, mu_bf, xrt);
    hipLaunchKernelGGL(k_conv2_mfma, dim3(NN / 128, CC / 128, BB), dim3(256), 0, stream,
                       w2bf, xrt, gamma, beta, mean, var, x, out);
}

// Round 5
// 446.201 us; speedup vs baseline: 4.0650x; 1.0765x over previous
//
#include <hip/hip_runtime.h>

typedef __bf16 bf16x8 __attribute__((ext_vector_type(8)));
typedef __bf16 bf16x4 __attribute__((ext_vector_type(4)));
typedef float f32x4 __attribute__((ext_vector_type(4)));

constexpr int CC = 512;   // channels
constexpr int KK = 64;    // bases
constexpr int NN = 4096;  // h*w
constexpr int BB = 16;    // batch

// workspace layout (float units)
constexpr size_t R1_OFF    = 0;                     // XT bf16 [b][n][c]
constexpr size_t R2_OFF    = 16777216;              // XFT bf16 [b][n][c], later XRT bf16 [b][n][c]
constexpr size_t Z_OFF     = 33554432;              // Z  bf16 [b][n][k]
constexpr size_t ZT_OFF    = 35651584;              // ZT bf16 [b][k][n]
constexpr size_t MUACC_OFF = 37748736;              // fp32 [b][c][k]
constexpr size_t ZSUM_OFF  = 38273024;              // fp32 [b][k]
constexpr size_t MUBF_OFF  = 38274048;              // bf16 [b][c][k]
constexpr size_t MUTBF_OFF = 38536192;              // bf16 [b][k][c]
constexpr size_t W1BF_OFF  = 38798336;              // bf16 [o][c]
constexpr size_t W2BF_OFF  = 38929408;              // bf16 [o][c]
// XFC bf16 [b][c][n] lives in d_out (dead until conv2 writes the final output)

// ---------------- fp32 -> bf16 convert (weights) ----------------
__global__ __launch_bounds__(256) void k_cvt(const float* __restrict__ src,
                                             __bf16* __restrict__ dst, int n8) {
    int i = blockIdx.x * 256 + threadIdx.x;
    if (i < n8) {
        const float4* s4 = (const float4*)src;
        float4 a = s4[i * 2], b = s4[i * 2 + 1];
        bf16x8 o;
        o[0] = (__bf16)a.x; o[1] = (__bf16)a.y; o[2] = (__bf16)a.z; o[3] = (__bf16)a.w;
        o[4] = (__bf16)b.x; o[5] = (__bf16)b.y; o[6] = (__bf16)b.z; o[7] = (__bf16)b.w;
        *(bf16x8*)&dst[(size_t)i * 8] = o;
    }
}

// ---------------- initial mu broadcast to both bf16 layouts ----------------
__global__ __launch_bounds__(256) void k_mu_bcast_bf(const float* __restrict__ mu_in,
                                                     __bf16* __restrict__ mu_bf,
                                                     __bf16* __restrict__ muT_bf) {
    int idx = blockIdx.x * 256 + threadIdx.x;
    if (idx < CC * KK) {
        int c = idx >> 6, k = idx & 63;
        __bf16 v = (__bf16)mu_in[idx];
        for (int b = 0; b < BB; ++b) {
            mu_bf[(size_t)b * CC * KK + idx] = v;
            muT_bf[((size_t)b * KK + k) * CC + c] = v;
        }
    }
}

// ---------------- X [b][c][n] fp32 -> XT [b][n][c] bf16 ----------------
__global__ __launch_bounds__(256) void k_xpose_cvt(const float* __restrict__ X,
                                                   __bf16* __restrict__ XT) {
    int n0 = blockIdx.x * 64, c0 = blockIdx.y * 64, b = blockIdx.z;
    __shared__ float T[64][65];
    int tid = threadIdx.x;
    const float* Xb = X + (size_t)b * CC * NN;
#pragma unroll
    for (int p = 0; p < 4; ++p) {
        int f4 = tid + p * 256;
        int row = f4 >> 4, col4 = (f4 & 15) * 4;
        float4 v = *(const float4*)&Xb[(size_t)(c0 + row) * NN + n0 + col4];
        T[row][col4 + 0] = v.x; T[row][col4 + 1] = v.y;
        T[row][col4 + 2] = v.z; T[row][col4 + 3] = v.w;
    }
    __syncthreads();
#pragma unroll
    for (int p = 0; p < 2; ++p) {
        int q = tid + p * 256;
        int nl = q >> 3, c8 = (q & 7) * 8;
        bf16x8 o;
#pragma unroll
        for (int j = 0; j < 8; ++j) o[j] = (__bf16)T[c8 + j][nl];
        *(bf16x8*)&XT[((size_t)b * NN + n0 + nl) * CC + c0 + c8] = o;
    }
}

// ---------------- conv1: XFT[b][n][o] (scatter) + XFC[b][o][n] (vectorized) ----------------
__global__ __launch_bounds__(256) void k_conv1_mfma(
    const __bf16* __restrict__ XT, const __bf16* __restrict__ W1,
    const float* __restrict__ bias, __bf16* __restrict__ XFT,
    __bf16* __restrict__ XFC) {
    __shared__ __bf16 As[2][128 * 32];
    __shared__ __bf16 Bs[2][128 * 32];
    __shared__ float sbias[128];
    int tid = threadIdx.x;
    int lane = tid & 63, wave = tid >> 6;
    int wm = wave >> 1, wn = wave & 1;
    int o0 = blockIdx.x * 128, n0 = blockIdx.y * 128, b = blockIdx.z;
    const __bf16* Ab = XT + ((size_t)b * NN + n0) * CC;
    const __bf16* Bb = W1 + (size_t)o0 * CC;
    if (tid < 128) sbias[tid] = bias[o0 + tid];

    f32x4 acc[4][4];
#pragma unroll
    for (int i = 0; i < 4; ++i)
#pragma unroll
        for (int j = 0; j < 4; ++j) acc[i][j] = f32x4{0.f, 0.f, 0.f, 0.f};

    int r0 = tid >> 2, k0c = tid & 3;
    int r1 = (tid + 256) >> 2, k1c = tid & 3;
    int w0 = r0 * 32 + (k0c ^ ((r0 >> 1) & 3)) * 8;
    int w1 = r1 * 32 + (k1c ^ ((r1 >> 1) & 3)) * 8;

    bf16x8 va0, va1, vb0, vb1;
    va0 = *(const bf16x8*)(Ab + (size_t)r0 * CC + k0c * 8);
    va1 = *(const bf16x8*)(Ab + (size_t)r1 * CC + k1c * 8);
    vb0 = *(const bf16x8*)(Bb + (size_t)r0 * CC + k0c * 8);
    vb1 = *(const bf16x8*)(Bb + (size_t)r1 * CC + k1c * 8);
    *(bf16x8*)&As[0][w0] = va0; *(bf16x8*)&As[0][w1] = va1;
    *(bf16x8*)&Bs[0][w0] = vb0; *(bf16x8*)&Bs[0][w1] = vb1;
    __syncthreads();

    for (int kt = 0; kt < 16; ++kt) {
        int s = kt & 1;
        if (kt < 15) {
            const __bf16* Ak = Ab + (kt + 1) * 32;
            const __bf16* Bk = Bb + (kt + 1) * 32;
            va0 = *(const bf16x8*)(Ak + (size_t)r0 * CC + k0c * 8);
            va1 = *(const bf16x8*)(Ak + (size_t)r1 * CC + k1c * 8);
            vb0 = *(const bf16x8*)(Bk + (size_t)r0 * CC + k0c * 8);
            vb1 = *(const bf16x8*)(Bk + (size_t)r1 * CC + k1c * 8);
        }
        bf16x8 af[4], bg[4];
#pragma unroll
        for (int f = 0; f < 4; ++f) {
            int ra = wm * 64 + f * 16 + (lane & 15);
            af[f] = *(const bf16x8*)&As[s][ra * 32 + (((lane >> 4) ^ ((ra >> 1) & 3))) * 8];
            int rb = wn * 64 + f * 16 + (lane & 15);
            bg[f] = *(const bf16x8*)&Bs[s][rb * 32 + (((lane >> 4) ^ ((rb >> 1) & 3))) * 8];
        }
#pragma unroll
        for (int i = 0; i < 4; ++i)
#pragma unroll
            for (int j = 0; j < 4; ++j)
                acc[i][j] = __builtin_amdgcn_mfma_f32_16x16x32_bf16(af[i], bg[j], acc[i][j], 0, 0, 0);
        if (kt < 15) {
            *(bf16x8*)&As[s ^ 1][w0] = va0; *(bf16x8*)&As[s ^ 1][w1] = va1;
            *(bf16x8*)&Bs[s ^ 1][w0] = vb0; *(bf16x8*)&Bs[s ^ 1][w1] = vb1;
        }
        __syncthreads();
    }

    int gq = lane >> 4, ln = lane & 15;
#pragma unroll
    for (int mf = 0; mf < 4; ++mf) {
#pragma unroll
        for (int nf = 0; nf < 4; ++nf) {
            int o_loc = wn * 64 + nf * 16 + ln;
            int n_loc4 = wm * 64 + mf * 16 + gq * 4;
            float bi = sbias[o_loc];
            // vectorized XFC [c][n] store: regs = 4 consecutive n at fixed o
            bf16x4 oc;
#pragma unroll
            for (int r = 0; r < 4; ++r) oc[r] = (__bf16)(acc[mf][nf][r] + bi);
            *(bf16x4*)&XFC[((size_t)b * CC + o0 + o_loc) * NN + n0 + n_loc4] = oc;
            // scattered XFT [n][c] store (2B per lane)
#pragma unroll
            for (int r = 0; r < 4; ++r) {
                XFT[((size_t)b * NN + n0 + n_loc4 + r) * CC + o0 + o_loc] = oc[r];
            }
        }
    }
}

// ---------------- conv2: OUT[c][n] = relu( BN(W2·XR) + X ); D[n][o] for float4 epilogue ----------------
__global__ __launch_bounds__(256) void k_conv2_mfma(
    const __bf16* __restrict__ W2, const __bf16* __restrict__ XRT,
    const float* __restrict__ gamma, const float* __restrict__ beta,
    const float* __restrict__ mean, const float* __restrict__ var,
    const float* __restrict__ Xres, float* __restrict__ Out) {
    __shared__ __bf16 As[2][128 * 32];   // XRT rows (n)
    __shared__ __bf16 Bs[2][128 * 32];   // W2 rows (o)
    __shared__ float sp0[128], sp1[128];
    int tid = threadIdx.x;
    int lane = tid & 63, wave = tid >> 6;
    int wm = wave >> 1, wn = wave & 1;
    int n0 = blockIdx.x * 128, m0 = blockIdx.y * 128, b = blockIdx.z;
    const __bf16* Ab = XRT + ((size_t)b * NN + n0) * CC;
    const __bf16* Bb = W2 + (size_t)m0 * CC;
    if (tid < 128) {
        float iv = gamma[m0 + tid] * rsqrtf(var[m0 + tid] + 1e-5f);
        sp0[tid] = iv;
        sp1[tid] = beta[m0 + tid] - mean[m0 + tid] * iv;
    }

    f32x4 acc[4][4];
#pragma unroll
    for (int i = 0; i < 4; ++i)
#pragma unroll
        for (int j = 0; j < 4; ++j) acc[i][j] = f32x4{0.f, 0.f, 0.f, 0.f};

    int r0 = tid >> 2, k0c = tid & 3;
    int r1 = (tid + 256) >> 2, k1c = tid & 3;
    int w0 = r0 * 32 + (k0c ^ ((r0 >> 1) & 3)) * 8;
    int w1 = r1 * 32 + (k1c ^ ((r1 >> 1) & 3)) * 8;

    bf16x8 va0, va1, vb0, vb1;
    va0 = *(const bf16x8*)(Ab + (size_t)r0 * CC + k0c * 8);
    va1 = *(const bf16x8*)(Ab + (size_t)r1 * CC + k1c * 8);
    vb0 = *(const bf16x8*)(Bb + (size_t)r0 * CC + k0c * 8);
    vb1 = *(const bf16x8*)(Bb + (size_t)r1 * CC + k1c * 8);
    *(bf16x8*)&As[0][w0] = va0; *(bf16x8*)&As[0][w1] = va1;
    *(bf16x8*)&Bs[0][w0] = vb0; *(bf16x8*)&Bs[0][w1] = vb1;
    __syncthreads();

    for (int kt = 0; kt < 16; ++kt) {
        int s = kt & 1;
        if (kt < 15) {
            const __bf16* Ak = Ab + (kt + 1) * 32;
            const __bf16* Bk = Bb + (kt + 1) * 32;
            va0 = *(const bf16x8*)(Ak + (size_t)r0 * CC + k0c * 8);
            va1 = *(const bf16x8*)(Ak + (size_t)r1 * CC + k1c * 8);
            vb0 = *(const bf16x8*)(Bk + (size_t)r0 * CC + k0c * 8);
            vb1 = *(const bf16x8*)(Bk + (size_t)r1 * CC + k1c * 8);
        }
        bf16x8 af[4], bg[4];
#pragma unroll
        for (int f = 0; f < 4; ++f) {
            int ra = wm * 64 + f * 16 + (lane & 15);
            af[f] = *(const bf16x8*)&As[s][ra * 32 + (((lane >> 4) ^ ((ra >> 1) & 3))) * 8];
            int rb = wn * 64 + f * 16 + (lane & 15);
            bg[f] = *(const bf16x8*)&Bs[s][rb * 32 + (((lane >> 4) ^ ((rb >> 1) & 3))) * 8];
        }
#pragma unroll
        for (int i = 0; i < 4; ++i)
#pragma unroll
            for (int j = 0; j < 4; ++j)
                acc[i][j] = __builtin_amdgcn_mfma_f32_16x16x32_bf16(af[i], bg[j], acc[i][j], 0, 0, 0);
        if (kt < 15) {
            *(bf16x8*)&As[s ^ 1][w0] = va0; *(bf16x8*)&As[s ^ 1][w1] = va1;
            *(bf16x8*)&Bs[s ^ 1][w0] = vb0; *(bf16x8*)&Bs[s ^ 1][w1] = vb1;
        }
        __syncthreads();
    }

    // epilogue: D rows = n (regs span 4 consecutive n), cols = o -> float4 load/store
    int gq = lane >> 4, ln = lane & 15;
#pragma unroll
    for (int mf = 0; mf < 4; ++mf) {
#pragma unroll
        for (int nf = 0; nf < 4; ++nf) {
            int o_loc = wn * 64 + nf * 16 + ln;
            int n_loc4 = wm * 64 + mf * 16 + gq * 4;
            size_t addr = ((size_t)b * CC + m0 + o_loc) * NN + n0 + n_loc4;
            float iv = sp0[o_loc], sh = sp1[o_loc];
            float4 xi = *(const float4*)&Xres[addr];
            float4 v;
            v.x = fmaxf(acc[mf][nf][0] * iv + sh + xi.x, 0.f);
            v.y = fmaxf(acc[mf][nf][1] * iv + sh + xi.y, 0.f);
            v.z = fmaxf(acc[mf][nf][2] * iv + sh + xi.z, 0.f);
            v.w = fmaxf(acc[mf][nf][3] * iv + sh + xi.w, 0.f);
            *(float4*)&Out[addr] = v;
        }
    }
}

// ---------------- zsoftmax: logits MFMA + in-register softmax + Z/ZT/zsum ----------------
__global__ __launch_bounds__(256) void k_zsoftmax_mfma(
    const __bf16* __restrict__ XFT, const __bf16* __restrict__ MUT,
    __bf16* __restrict__ Z, __bf16* __restrict__ ZT, float* __restrict__ ZSUM) {
    __shared__ __bf16 As[2][128 * 32];
    __shared__ __bf16 Bs[2][64 * 32];
    __shared__ __bf16 ZL[64][136];     // [k][n] tile for coalesced ZT writeout
    int tid = threadIdx.x;
    int lane = tid & 63, wave = tid >> 6;
    int n0 = blockIdx.x * 128, b = blockIdx.y;
    const __bf16* Ab = XFT + ((size_t)b * NN + n0) * CC;
    const __bf16* Bb = MUT + (size_t)b * KK * CC;

    f32x4 acc[2][4];
#pragma unroll
    for (int i = 0; i < 2; ++i)
#pragma unroll
        for (int j = 0; j < 4; ++j) acc[i][j] = f32x4{0.f, 0.f, 0.f, 0.f};

    int r0 = tid >> 2, k0c = tid & 3;
    int r1 = (tid + 256) >> 2, k1c = tid & 3;
    int w0 = r0 * 32 + (k0c ^ ((r0 >> 1) & 3)) * 8;
    int w1 = r1 * 32 + (k1c ^ ((r1 >> 1) & 3)) * 8;
    int rB = tid >> 2, kB = tid & 3;
    int wB = rB * 32 + (kB ^ ((rB >> 1) & 3)) * 8;

    bf16x8 va0, va1, vb0;
    va0 = *(const bf16x8*)(Ab + (size_t)r0 * CC + k0c * 8);
    va1 = *(const bf16x8*)(Ab + (size_t)r1 * CC + k1c * 8);
    vb0 = *(const bf16x8*)(Bb + (size_t)rB * CC + kB * 8);
    *(bf16x8*)&As[0][w0] = va0; *(bf16x8*)&As[0][w1] = va1;
    *(bf16x8*)&Bs[0][wB] = vb0;
    __syncthreads();

    for (int kt = 0; kt < 16; ++kt) {
        int s = kt & 1;
        if (kt < 15) {
            const __bf16* Ak = Ab + (kt + 1) * 32;
            const __bf16* Bk = Bb + (kt + 1) * 32;
            va0 = *(const bf16x8*)(Ak + (size_t)r0 * CC + k0c * 8);
            va1 = *(const bf16x8*)(Ak + (size_t)r1 * CC + k1c * 8);
            vb0 = *(const bf16x8*)(Bk + (size_t)rB * CC + kB * 8);
        }
        bf16x8 af[2], bg[4];
#pragma unroll
        for (int f = 0; f < 2; ++f) {
            int ra = wave * 32 + f * 16 + (lane & 15);
            af[f] = *(const bf16x8*)&As[s][ra * 32 + (((lane >> 4) ^ ((ra >> 1) & 3))) * 8];
        }
#pragma unroll
        for (int f = 0; f < 4; ++f) {
            int rb = f * 16 + (lane & 15);
            bg[f] = *(const bf16x8*)&Bs[s][rb * 32 + (((lane >> 4) ^ ((rb >> 1) & 3))) * 8];
        }
#pragma unroll
        for (int i = 0; i < 2; ++i)
#pragma unroll
            for (int j = 0; j < 4; ++j)
                acc[i][j] = __builtin_amdgcn_mfma_f32_16x16x32_bf16(af[i], bg[j], acc[i][j], 0, 0, 0);
        if (kt < 15) {
            *(bf16x8*)&As[s ^ 1][w0] = va0; *(bf16x8*)&As[s ^ 1][w1] = va1;
            *(bf16x8*)&Bs[s ^ 1][wB] = vb0;
        }
        __syncthreads();
    }

    // softmax over k=64 per row; each row owned by 16 lanes (same lane>>4 group)
    int gq = lane >> 4, ln = lane & 15;
    float zp[4] = {0.f, 0.f, 0.f, 0.f};
#pragma unroll
    for (int mf = 0; mf < 2; ++mf) {
#pragma unroll
        for (int r = 0; r < 4; ++r) {
            float mx = fmaxf(fmaxf(acc[mf][0][r], acc[mf][1][r]),
                             fmaxf(acc[mf][2][r], acc[mf][3][r]));
            mx = fmaxf(mx, __shfl_xor(mx, 1));
            mx = fmaxf(mx, __shfl_xor(mx, 2));
            mx = fmaxf(mx, __shfl_xor(mx, 4));
            mx = fmaxf(mx, __shfl_xor(mx, 8));
            float e[4];
            float ssum = 0.f;
#pragma unroll
            for (int nf = 0; nf < 4; ++nf) { e[nf] = expf(acc[mf][nf][r] - mx); ssum += e[nf]; }
            ssum += __shfl_xor(ssum, 1);
            ssum += __shfl_xor(ssum, 2);
            ssum += __shfl_xor(ssum, 4);
            ssum += __shfl_xor(ssum, 8);
            float inv = 1.0f / ssum;
            int n_loc = wave * 32 + mf * 16 + gq * 4 + r;
            size_t zrow = ((size_t)b * NN + n0 + n_loc) * KK;
#pragma unroll
            for (int nf = 0; nf < 4; ++nf) {
                float zv = e[nf] * inv;
                zp[nf] += zv;
                int k = nf * 16 + ln;
                __bf16 zb = (__bf16)zv;
                Z[zrow + k] = zb;
                ZL[k][n_loc] = zb;
            }
        }
    }
#pragma unroll
    for (int nf = 0; nf < 4; ++nf) {
        float t = zp[nf];
        t += __shfl_xor(t, 16);
        t += __shfl_xor(t, 32);
        if (lane < 16) atomicAdd(&ZSUM[b * KK + nf * 16 + ln], t);
    }
    __syncthreads();
    // coalesced ZT writeout: 64 k-rows x 128 n, bf16x8 chunks
#pragma unroll
    for (int p = 0; p < 4; ++p) {
        int ci = tid + p * 256;
        int kr = ci >> 4, ch = (ci & 15) * 8;
        bf16x8 v = *(const bf16x8*)&ZL[kr][ch];
        *(bf16x8*)&ZT[((size_t)b * KK + kr) * NN + n0 + ch] = v;
    }
}

// ---------------- muacc: MUACC[c][k] += sum_n XFC[c][n]·ZT[k][n], split-K over n ----------------
__global__ __launch_bounds__(256) void k_muacc_mfma(
    const __bf16* __restrict__ XFC, const __bf16* __restrict__ ZT,
    float* __restrict__ MUACC) {
    __shared__ __bf16 As[2][128 * 32];
    __shared__ __bf16 Bs[2][64 * 32];
    int tid = threadIdx.x;
    int lane = tid & 63, wave = tid >> 6;
    int wm = wave >> 1, wn = wave & 1;
    int c0 = (blockIdx.x & 3) * 128, sp = blockIdx.x >> 2, b = blockIdx.y;
    size_t nbase = (size_t)sp * 512;
    const __bf16* Ab = XFC + ((size_t)b * CC + c0) * NN + nbase;
    const __bf16* Bb = ZT + (size_t)b * KK * NN + nbase;

    f32x4 acc[4][2];
#pragma unroll
    for (int i = 0; i < 4; ++i)
#pragma unroll
        for (int j = 0; j < 2; ++j) acc[i][j] = f32x4{0.f, 0.f, 0.f, 0.f};

    int r0 = tid >> 2, k0c = tid & 3;
    int r1 = (tid + 256) >> 2, k1c = tid & 3;
    int w0 = r0 * 32 + (k0c ^ ((r0 >> 1) & 3)) * 8;
    int w1 = r1 * 32 + (k1c ^ ((r1 >> 1) & 3)) * 8;
    int rB = tid >> 2, kB = tid & 3;
    int wB = rB * 32 + (kB ^ ((rB >> 1) & 3)) * 8;

    bf16x8 va0, va1, vb0;
    va0 = *(const bf16x8*)(Ab + (size_t)r0 * NN + k0c * 8);
    va1 = *(const bf16x8*)(Ab + (size_t)r1 * NN + k1c * 8);
    vb0 = *(const bf16x8*)(Bb + (size_t)rB * NN + kB * 8);
    *(bf16x8*)&As[0][w0] = va0; *(bf16x8*)&As[0][w1] = va1;
    *(bf16x8*)&Bs[0][wB] = vb0;
    __syncthreads();

    for (int kt = 0; kt < 16; ++kt) {
        int s = kt & 1;
        if (kt < 15) {
            const __bf16* Ak = Ab + (kt + 1) * 32;
            const __bf16* Bk = Bb + (kt + 1) * 32;
            va0 = *(const bf16x8*)(Ak + (size_t)r0 * NN + k0c * 8);
            va1 = *(const bf16x8*)(Ak + (size_t)r1 * NN + k1c * 8);
            vb0 = *(const bf16x8*)(Bk + (size_t)rB * NN + kB * 8);
        }
        bf16x8 af[4], bg[2];
#pragma unroll
        for (int f = 0; f < 4; ++f) {
            int ra = wm * 64 + f * 16 + (lane & 15);
            af[f] = *(const bf16x8*)&As[s][ra * 32 + (((lane >> 4) ^ ((ra >> 1) & 3))) * 8];
        }
#pragma unroll
        for (int f = 0; f < 2; ++f) {
            int rb = wn * 32 + f * 16 + (lane & 15);
            bg[f] = *(const bf16x8*)&Bs[s][rb * 32 + (((lane >> 4) ^ ((rb >> 1) & 3))) * 8];
        }
#pragma unroll
        for (int i = 0; i < 4; ++i)
#pragma unroll
            for (int j = 0; j < 2; ++j)
                acc[i][j] = __builtin_amdgcn_mfma_f32_16x16x32_bf16(af[i], bg[j], acc[i][j], 0, 0, 0);
        if (kt < 15) {
            *(bf16x8*)&As[s ^ 1][w0] = va0; *(bf16x8*)&As[s ^ 1][w1] = va1;
            *(bf16x8*)&Bs[s ^ 1][wB] = vb0;
        }
        __syncthreads();
    }

    int gq = lane >> 4, ln = lane & 15;
#pragma unroll
    for (int mf = 0; mf < 4; ++mf) {
#pragma unroll
        for (int r = 0; r < 4; ++r) {
            int row = wm * 64 + mf * 16 + gq * 4 + r;
#pragma unroll
            for (int nf = 0; nf < 2; ++nf) {
                int col = wn * 32 + nf * 16 + ln;
                atomicAdd(&MUACC[((size_t)b * CC + c0 + row) * KK + col], acc[mf][nf][r]);
            }
        }
    }
}

// ---------------- munorm -> bf16 mu (both layouts) ----------------
__global__ __launch_bounds__(64) void k_munorm_bf(
    const float* __restrict__ MUACC, const float* __restrict__ ZSUM,
    __bf16* __restrict__ mu_bf, __bf16* __restrict__ muT_bf) {
    int k = blockIdx.x;
    int b = blockIdx.y;
    int lane = threadIdx.x;
    float scale = 1.0f / (1e-6f + ZSUM[b * KK + k]);
    float v[8];
    float ss = 0.f;
#pragma unroll
    for (int i = 0; i < 8; ++i) {
        v[i] = MUACC[(size_t)b * CC * KK + (size_t)(lane + i * 64) * KK + k] * scale;
        ss += v[i] * v[i];
    }
    for (int off = 32; off; off >>= 1) ss += __shfl_xor(ss, off);
    float nrm = 1.0f / (1e-6f + sqrtf(ss));
#pragma unroll
    for (int i = 0; i < 8; ++i) {
        int c = lane + i * 64;
        __bf16 o = (__bf16)(v[i] * nrm);
        mu_bf[((size_t)b * CC + c) * KK + k] = o;
        muT_bf[((size_t)b * KK + k) * CC + c] = o;
    }
}

// ---------------- xr: XRT[b][n][c] = bf16(relu( sum_k Z[n][k]·mu[c][k] )), K=64 ----------------
__global__ __launch_bounds__(256) void k_xr_mfma(
    const __bf16* __restrict__ Zm, const __bf16* __restrict__ MUB,
    __bf16* __restrict__ XRT) {
    __shared__ __bf16 As[128 * 64];
    __shared__ __bf16 Bs[128 * 64];
    int tid = threadIdx.x;
    int lane = tid & 63, wave = tid >> 6;
    int wm = wave >> 1, wn = wave & 1;
    int n0 = blockIdx.x * 128, c0 = blockIdx.y * 128, b = blockIdx.z;
    const __bf16* Ab = Zm + ((size_t)b * NN + n0) * KK;
    const __bf16* Bb = MUB + ((size_t)b * CC + c0) * KK;
#pragma unroll
    for (int p = 0; p < 4; ++p) {
        int idx = tid + p * 256;
        int r = idx >> 3, ch = idx & 7;
        int woff = r * 64 + ((ch ^ (r & 7)) * 8);
        *(bf16x8*)&As[woff] = *(const bf16x8*)(Ab + (size_t)r * KK + ch * 8);
        *(bf16x8*)&Bs[woff] = *(const bf16x8*)(Bb + (size_t)r * KK + ch * 8);
    }
    __syncthreads();

    f32x4 acc[4][4];
#pragma unroll
    for (int i = 0; i < 4; ++i)
#pragma unroll
        for (int j = 0; j < 4; ++j) acc[i][j] = f32x4{0.f, 0.f, 0.f, 0.f};

    int gq = lane >> 4, ln = lane & 15;
#pragma unroll
    for (int ks = 0; ks < 2; ++ks) {
        bf16x8 af[4], bg[4];
#pragma unroll
        for (int f = 0; f < 4; ++f) {
            int ra = wm * 64 + f * 16 + ln;
            af[f] = *(const bf16x8*)&As[ra * 64 + (((ks * 4 + gq) ^ (ra & 7))) * 8];
            int rb = wn * 64 + f * 16 + ln;
            bg[f] = *(const bf16x8*)&Bs[rb * 64 + (((ks * 4 + gq) ^ (rb & 7))) * 8];
        }
#pragma unroll
        for (int i = 0; i < 4; ++i)
#pragma unroll
            for (int j = 0; j < 4; ++j)
                acc[i][j] = __builtin_amdgcn_mfma_f32_16x16x32_bf16(af[i], bg[j], acc[i][j], 0, 0, 0);
    }

#pragma unroll
    for (int mf = 0; mf < 4; ++mf) {
#pragma unroll
        for (int r = 0; r < 4; ++r) {
            int n_loc = wm * 64 + mf * 16 + gq * 4 + r;
            size_t orow = ((size_t)b * NN + n0 + n_loc) * CC + c0 + wn * 64;
#pragma unroll
            for (int nf = 0; nf < 4; ++nf) {
                XRT[orow + nf * 16 + ln] = (__bf16)fmaxf(acc[mf][nf][r], 0.f);
            }
        }
    }
}

extern "C" void kernel_launch(void* const* d_in, const int* in_sizes, int n_in,
                              void* d_out, int out_size, void* d_ws, size_t ws_size,
                              hipStream_t stream) {
    const float* x     = (const float*)d_in[0];
    const float* w1    = (const float*)d_in[1];
    const float* b1    = (const float*)d_in[2];
    const float* mu_in = (const float*)d_in[3];
    const float* w2    = (const float*)d_in[4];
    const float* gamma = (const float*)d_in[5];
    const float* beta  = (const float*)d_in[6];
    const float* mean  = (const float*)d_in[7];
    const float* var   = (const float*)d_in[8];
    float* out = (float*)d_out;
    float* ws  = (float*)d_ws;

    __bf16* xt    = (__bf16*)(ws + R1_OFF);
    __bf16* xft   = (__bf16*)(ws + R2_OFF);    // region 2: XFT, later XRT
    __bf16* xrt   = (__bf16*)(ws + R2_OFF);
    __bf16* xfc   = (__bf16*)d_out;            // XFC staged in d_out (dead until conv2 writes)
    __bf16* zbf   = (__bf16*)(ws + Z_OFF);
    __bf16* ztbf  = (__bf16*)(ws + ZT_OFF);
    float*  muacc = ws + MUACC_OFF;
    float*  zsum  = ws + ZSUM_OFF;
    __bf16* mu_bf = (__bf16*)(ws + MUBF_OFF);
    __bf16* muT_bf= (__bf16*)(ws + MUTBF_OFF);
    __bf16* w1bf  = (__bf16*)(ws + W1BF_OFF);
    __bf16* w2bf  = (__bf16*)(ws + W2BF_OFF);

    hipLaunchKernelGGL(k_cvt, dim3(128), dim3(256), 0, stream, w1, w1bf, CC * CC / 8);
    hipLaunchKernelGGL(k_cvt, dim3(128), dim3(256), 0, stream, w2, w2bf, CC * CC / 8);
    hipLaunchKernelGGL(k_mu_bcast_bf, dim3(128), dim3(256), 0, stream, mu_in, mu_bf, muT_bf);
    hipLaunchKernelGGL(k_xpose_cvt, dim3(NN / 64, CC / 64, BB), dim3(256), 0, stream, x, xt);
    hipLaunchKernelGGL(k_conv1_mfma, dim3(CC / 128, NN / 128, BB), dim3(256), 0, stream,
                       xt, w1bf, b1, xft, xfc);
    for (int it = 0; it < 3; ++it) {
        hipMemsetAsync(muacc, 0, (size_t)(BB * CC * KK + BB * KK) * sizeof(float), stream);
        hipLaunchKernelGGL(k_zsoftmax_mfma, dim3(NN / 128, BB), dim3(256), 0, stream,
                           xft, muT_bf, zbf, ztbf, zsum);
        hipLaunchKernelGGL(k_muacc_mfma, dim3(32, BB), dim3(256), 0, stream, xfc, ztbf, muacc);
        hipLaunchKernelGGL(k_munorm_bf, dim3(KK, BB), dim3(64), 0, stream, muacc, zsum,
                           mu_bf, muT_bf);
    }
    hipLaunchKernelGGL(k_xr_mfma, dim3(NN / 128, CC / 128, BB), dim3(256), 0, stream,
                       zbf, mu_bf, xrt);
    hipLaunchKernelGGL(k_conv2_mfma, dim3(NN / 128, CC / 128, BB), dim3(256), 0, stream,
                       w2bf, xrt, gamma, beta, mean, var, x, out);
}